// Round 6
// baseline (279.610 us; speedup 1.0000x reference)
//
#include <hip/hip_runtime.h>
#include <hip/hip_bf16.h>

// Problem constants (fixed by the reference)
#define B_  4
#define T_  2048
#define D_  1024
#define H_  16
#define HD_ 64
#define THREE_D (3 * D_)
#define TWO_D   (2 * D_)

typedef short s16x8 __attribute__((ext_vector_type(8)));   // 8 bf16 (4 VGPRs)
typedef float f32x4 __attribute__((ext_vector_type(4)));   // MFMA C/D frag
typedef unsigned short u16;
typedef unsigned short u16x4 __attribute__((ext_vector_type(4)));

static __device__ __forceinline__ s16x8 load8(const u16* p) {
    return *reinterpret_cast<const s16x8*>(p);
}
static __device__ __forceinline__ u16 f2bf(float f) {
    __hip_bfloat16 h = __float2bfloat16(f);
    return *reinterpret_cast<u16*>(&h);
}
// truncating fp32->bf16 (1 shift). P>=0 and osum uses the same truncated
// values, so the avg -0.2% bias cancels in the softmax normalization.
static __device__ __forceinline__ u16 bftrunc(float f) {
    unsigned u; __builtin_memcpy(&u, &f, 4); return (u16)(u >> 16);
}

// global -> LDS direct DMA, 16B per lane (m97 ladder step: 517 -> 874 TF)
static __device__ __forceinline__ void gload_lds16(const u16* g, u16* l) {
#if __has_builtin(__builtin_amdgcn_global_load_lds)
    __builtin_amdgcn_global_load_lds(
        (__attribute__((address_space(1))) void*)g,
        (__attribute__((address_space(3))) void*)l, 16, 0, 0);
#else
    *reinterpret_cast<s16x8*>(l) = load8(g);
#endif
}

// ---------------------------------------------------------------------------
// fp32 -> bf16 convert (RNE), 4 elements/thread.
// ---------------------------------------------------------------------------
__global__ __launch_bounds__(256) void cvt_f32_bf16(
    const float* __restrict__ in, u16* __restrict__ out, int n)
{
    const int i = (blockIdx.x * 256 + threadIdx.x) * 4;
    if (i < n) {
        const float4 f = *reinterpret_cast<const float4*>(in + i);
        u16x4 r;
        r.x = f2bf(f.x); r.y = f2bf(f.y); r.z = f2bf(f.z); r.w = f2bf(f.w);
        *reinterpret_cast<u16x4*>(out + i) = r;
    }
}

// ---------------------------------------------------------------------------
// QKV GEMM v2: 256x256 tile, BK=64, 8 waves, deep-cover phase pipeline.
//
// Fixes vs v1 (85us, 4.7M bank conflicts, 1-phase load cover):
//  (a) FULL 3-bit LDS swizzle: rows are 128B = 32 dwords, so banks depend
//      only on the column; frag reads need chunk ^= (row&7) over all 8
//      16B-slots (v1's row&4 spread over 4 -> 2x LDS cycles). Involution
//      applied to the pre-swizzled GLOBAL source (DMA dest stays linear,
//      m104/m173 both-sides rule) and to the ds_read chunk index.
//      LDS[r][c] = G[r][c ^ (r&7)]; read of logical c at c ^ (r&7).
//  (b) QUADRANT-ROTATED consumption for >=3-phase load cover: group g
//      (K-tile g, dbuf g&1) has 4 phases; ALL waves compute quadrant
//      (mh,nh) = (0,0),(1,0),(0,1),(1,1) at phases 1..4, accumulating
//      acc[q]. Staging of tile g+1 (into dbuf (g+1)&1) is ordered
//      {B0,A0,A1,B1} at phases 1..4, so the halves phase p consumes were
//      staged 3-4 phases earlier (~240-480 cyc of MFMA cover vs ~200-400
//      cyc L2 latency). Uniform s_waitcnt vmcnt(6) after each phase's
//      stage = 3 half-tiles in flight (m201 steady state), never 0.
//      Race audit: a half's last read is >=2 phase-barriers before its
//      overwrite is ISSUED (writes cannot land before issue); per-wave
//      vmcnt retires that wave's own staged chunks before it reaches the
//      phase barrier, so every post-barrier ds_read sees landed data.
//  Epilogue: cols [0,2048) -> Q*qsc / K bf16 into qk; [2048,3072) -> V
//  written transposed into vt[(b*16+h)*64+f][T] (packed b64).
// ---------------------------------------------------------------------------
__global__ __launch_bounds__(512, 2) void gemm256_qkv(
    const u16* __restrict__ A, const u16* __restrict__ Bm,
    u16* __restrict__ Cq, u16* __restrict__ vt,
    float qsc, int M, int N, int K, int lda, int ldb)
{
    const int ntiles = N >> 8;                    // 12
    const int nwg = (M >> 8) * ntiles;            // 384 (divisible by 8)
    const int cpx = nwg >> 3;
    const int wg = ((int)blockIdx.x & 7) * cpx + ((int)blockIdx.x >> 3);
    const int mt = wg / ntiles, nt = wg % ntiles;
    const int m0 = mt << 8, n0 = nt << 8;

    const int tid  = threadIdx.x;
    const int lane = tid & 63;
    const int l15  = lane & 15;
    const int quad = lane >> 4;
    const int wave = tid >> 6;
    const int wr   = wave >> 2;      // 0..1: 64-row band within a 128-row half
    const int wc   = wave & 3;       // 0..3: 32-row band within a 128-col half

    __shared__ u16 Ash[2][2][128 * 64];   // [dbuf][half][row*64+k], 64 KB
    __shared__ u16 Bsh[2][2][128 * 64];   // 64 KB; total 128 KB

    f32x4 acc[4][4][2] = {};              // [quadrant][mf][nf]

    // staging: thread t covers rows t>>3 and (t>>3)+64 of a half, 16B chunk
    // t&7, with the source column pre-swizzled by the row (involution).
    const int srow = tid >> 3;            // 0..63
    const int scol = ((tid & 7) ^ (srow & 7)) * 8;   // u16 units
    const u16* Ag = A  + (size_t)(m0 + srow) * lda + scol;
    const u16* Bg = Bm + (size_t)(n0 + srow) * ldb + scol;

#define STG(Xg, Xsh, db, h, kt, ld) do {                                     \
        gload_lds16(Xg + (size_t)((h) * 128)      * (ld) + (size_t)(kt) * 64,\
                    &Xsh[db][h][(size_t)tid * 8]);                           \
        gload_lds16(Xg + (size_t)((h) * 128 + 64) * (ld) + (size_t)(kt) * 64,\
                    &Xsh[db][h][(size_t)(tid + 512) * 8]);                   \
    } while (0)

// u16 offset of the b128 frag at (row, k-half) in a [128][64] half,
// swizzle-corrected: logical chunk = kh*4 + quad, stored at chunk^(row&7).
#define LOFF(row, kh) ((row) * 64 + ((((kh) * 4 + quad) ^ ((row) & 7)) * 8))

#define COMPUTE(dc, q, mh, nh) do {                                          \
        asm volatile("s_waitcnt vmcnt(6)" ::: "memory");                     \
        asm volatile("s_barrier" ::: "memory");                              \
        s16x8 af[4][2], bfr[2][2];                                           \
        _Pragma("unroll")                                                    \
        for (int mf = 0; mf < 4; ++mf) {                                     \
            const int ra = wr * 64 + mf * 16 + l15;                          \
            af[mf][0] = *reinterpret_cast<const s16x8*>(&Ash[dc][mh][LOFF(ra, 0)]); \
            af[mf][1] = *reinterpret_cast<const s16x8*>(&Ash[dc][mh][LOFF(ra, 1)]); \
        }                                                                    \
        _Pragma("unroll")                                                    \
        for (int nf = 0; nf < 2; ++nf) {                                     \
            const int rb = wc * 32 + nf * 16 + l15;                          \
            bfr[nf][0] = *reinterpret_cast<const s16x8*>(&Bsh[dc][nh][LOFF(rb, 0)]); \
            bfr[nf][1] = *reinterpret_cast<const s16x8*>(&Bsh[dc][nh][LOFF(rb, 1)]); \
        }                                                                    \
        __builtin_amdgcn_s_setprio(1);                                       \
        _Pragma("unroll")                                                    \
        for (int mf = 0; mf < 4; ++mf)                                       \
            _Pragma("unroll")                                                \
            for (int nf = 0; nf < 2; ++nf) {                                 \
                acc[q][mf][nf] = __builtin_amdgcn_mfma_f32_16x16x32_bf16(    \
                    af[mf][0], bfr[nf][0], acc[q][mf][nf], 0, 0, 0);         \
                acc[q][mf][nf] = __builtin_amdgcn_mfma_f32_16x16x32_bf16(    \
                    af[mf][1], bfr[nf][1], acc[q][mf][nf], 0, 0, 0);         \
            }                                                                \
        __builtin_amdgcn_s_setprio(0);                                       \
        asm volatile("s_barrier" ::: "memory");                              \
    } while (0)

    // prologue: tile 0, staged in consumption-rotation order B0 A0 A1 B1
    STG(Bg, Bsh, 0, 0, 0, ldb);
    STG(Ag, Ash, 0, 0, 0, lda);
    STG(Ag, Ash, 0, 1, 0, lda);
    STG(Bg, Bsh, 0, 1, 0, ldb);

    const int nkt = K >> 6;               // 16
    for (int g = 0; g < nkt; ++g) {
        const int dc = g & 1, dn = dc ^ 1;
        const int ts = (g + 1) & (nkt - 1);   // last group re-stages tile 0
        STG(Bg, Bsh, dn, 0, ts, ldb);  COMPUTE(dc, 0, 0, 0);
        STG(Ag, Ash, dn, 0, ts, lda);  COMPUTE(dc, 1, 1, 0);
        STG(Ag, Ash, dn, 1, ts, lda);  COMPUTE(dc, 2, 0, 1);
        STG(Bg, Bsh, dn, 1, ts, ldb);  COMPUTE(dc, 3, 1, 1);
    }
    asm volatile("s_waitcnt vmcnt(0)" ::: "memory");
#undef STG
#undef LOFF
#undef COMPUTE

    // Epilogue. C/D layout: row = quad*4 + r, col = l15.
    #pragma unroll
    for (int q = 0; q < 4; ++q) {
        const int mh = q & 1, nh = q >> 1;
        #pragma unroll
        for (int nf = 0; nf < 2; ++nf) {
            const int col = n0 + nh * 128 + wc * 32 + nf * 16 + l15;
            if (col < TWO_D) {               // Q (scaled) or K -> qk buffer
                const float sc = (col < D_) ? qsc : 1.0f;
                #pragma unroll
                for (int mf = 0; mf < 4; ++mf) {
                    const int row = m0 + mh * 128 + wr * 64 + mf * 16 + quad * 4;
                    #pragma unroll
                    for (int r = 0; r < 4; ++r)
                        Cq[(size_t)(row + r) * TWO_D + col] = f2bf(acc[q][mf][nf][r] * sc);
                }
            } else {                         // V -> transposed vt, packed b64
                const int vc = col - TWO_D;  // h*64 + f
                #pragma unroll
                for (int mf = 0; mf < 4; ++mf) {
                    const int row = m0 + mh * 128 + wr * 64 + mf * 16 + quad * 4;
                    const int bb = row >> 11, t = row & (T_ - 1);
                    u16x4 pk;
                    #pragma unroll
                    for (int r = 0; r < 4; ++r) pk[r] = f2bf(acc[q][mf][nf][r]);
                    *reinterpret_cast<u16x4*>(
                        vt + ((size_t)(bb * H_ * HD_) + vc) * T_ + t) = pk;
                }
            }
        }
    }
}

// ---------------------------------------------------------------------------
// m97-style GEMM, BK=64 as two 32-wide panels. C = A @ Bm^T.
// MODE 0: fp32 out + fp32 bias (projection GEMM).
// ---------------------------------------------------------------------------
template<int MODE>
__global__ __launch_bounds__(256) void gemm_bt128(
    const u16* __restrict__ A,
    const u16* __restrict__ Bm,
    void* __restrict__ Cv,
    const float* __restrict__ bias,
    int M, int N, int K, int lda, int ldb, int ldc,
    float qsc, u16* __restrict__ vt)
{
    const int ntiles = N >> 7;
    const int mt = blockIdx.x / ntiles;
    const int nt = blockIdx.x % ntiles;
    const int m0 = mt * 128, n0 = nt * 128;
    const int tid  = threadIdx.x;
    const int lane = tid & 63;
    const int l15  = lane & 15;
    const int quad = lane >> 4;
    const int wave = tid >> 6;
    const int wm = (wave >> 1) * 64;   // wave m-offset in tile
    const int wn = (wave & 1) * 64;    // wave n-offset in tile

    __shared__ u16 A_sh[2][128 * 32];  // [panel][row*32 + k], linear chunks
    __shared__ u16 B_sh[2][128 * 32];

    f32x4 acc[4][4] = {};

    // staging per panel: 512 chunks of 16B; thread t handles chunks t, t+256
    const int c0 = tid, c1 = tid + 256;
    const int ar0 = c0 >> 2, as0 = (c0 & 3) * 8;
    const int ar1 = c1 >> 2, as1 = (c1 & 3) * 8;
    const u16* Ag0 = A  + (size_t)(m0 + ar0) * lda + as0;
    const u16* Ag1 = A  + (size_t)(m0 + ar1) * lda + as1;
    const u16* Bg0 = Bm + (size_t)(n0 + ar0) * ldb + as0;
    const u16* Bg1 = Bm + (size_t)(n0 + ar1) * ldb + as1;

    for (int k0 = 0; k0 < K; k0 += 64) {
        __syncthreads();                  // prior iteration's LDS reads done
        #pragma unroll
        for (int p = 0; p < 2; ++p) {
            gload_lds16(Ag0 + k0 + p * 32, &A_sh[p][c0 * 8]);
            gload_lds16(Ag1 + k0 + p * 32, &A_sh[p][c1 * 8]);
            gload_lds16(Bg0 + k0 + p * 32, &B_sh[p][c0 * 8]);
            gload_lds16(Bg1 + k0 + p * 32, &B_sh[p][c1 * 8]);
        }
        __syncthreads();                  // drains vmcnt before barrier

        #pragma unroll
        for (int p = 0; p < 2; ++p) {
            s16x8 a[4], b[4];
            #pragma unroll
            for (int i = 0; i < 4; ++i) {
                a[i] = *reinterpret_cast<const s16x8*>(&A_sh[p][(wm + i * 16 + l15) * 32 + quad * 8]);
                b[i] = *reinterpret_cast<const s16x8*>(&B_sh[p][(wn + i * 16 + l15) * 32 + quad * 8]);
            }
            #pragma unroll
            for (int mi = 0; mi < 4; ++mi)
                #pragma unroll
                for (int ni = 0; ni < 4; ++ni)
                    acc[mi][ni] = __builtin_amdgcn_mfma_f32_16x16x32_bf16(
                        a[mi], b[ni], acc[mi][ni], 0, 0, 0);
        }
    }

    // Epilogue. C/D layout: row = quad*4 + r, col = lane&15
    #pragma unroll
    for (int ni = 0; ni < 4; ++ni) {
        const int col = n0 + wn + ni * 16 + l15;
        if (MODE == 0) {
            const float bv = bias ? bias[col] : 0.0f;
            #pragma unroll
            for (int mi = 0; mi < 4; ++mi) {
                const int row = m0 + wm + mi * 16 + quad * 4;
                #pragma unroll
                for (int r = 0; r < 4; ++r)
                    ((float*)Cv)[(size_t)(row + r) * ldc + col] = acc[mi][ni][r] + bv;
            }
        } else {
            if (col < TWO_D) {               // Q (scaled) or K -> qk buffer
                const float sc = (col < D_) ? qsc : 1.0f;
                #pragma unroll
                for (int mi = 0; mi < 4; ++mi) {
                    const int row = m0 + wm + mi * 16 + quad * 4;
                    #pragma unroll
                    for (int r = 0; r < 4; ++r)
                        ((u16*)Cv)[(size_t)(row + r) * ldc + col] = f2bf(acc[mi][ni][r] * sc);
                }
            } else {                         // V -> transposed vt, packed b64
                const int vc = col - TWO_D;  // h*64 + f
                #pragma unroll
                for (int mi = 0; mi < 4; ++mi) {
                    const int row = m0 + wm + mi * 16 + quad * 4;
                    const int bb = row >> 11, t = row & (T_ - 1);
                    u16x4 pk;
                    #pragma unroll
                    for (int r = 0; r < 4; ++r) pk[r] = f2bf(acc[mi][ni][r]);
                    *reinterpret_cast<u16x4*>(
                        vt + ((size_t)(bb * H_ * HD_) + vc) * T_ + t) = pk;
                }
            }
        }
    }
}

// ---------------------------------------------------------------------------
// Causal flash attention v6 (proven 75.4us). Block = 4 waves, Q-tile 128
// (32/wave), KV-tile 64; K and V staged in LDS (stride-72 pad, b128 frag
// reads). S computed TRANSPOSED via mfma(A=kf, B=qf); P packs into b64 LDS
// writes; PV reads natural [qrow][key] layout, b128. Q pre-scaled by
// (1/sqrt(64))*log2e in GEMM1; no running max; rowsum via ones-MFMA; qmap
// balances per-CU work.
// ---------------------------------------------------------------------------
__global__ __launch_bounds__(256) void flash_attn6(
    const u16* __restrict__ qk, const u16* __restrict__ vt,
    u16* __restrict__ out)   // [B*T, D] bf16
{
    const int cls = blockIdx.x >> 6;          // 0..15
    const int bh  = blockIdx.x & 63;
    const int qmap[16] = {15,14,13,12, 8,9,10,11, 7,6,5,4, 0,1,2,3};
    const int qt = qmap[cls];
    const int h = bh & 15, b = bh >> 4;
    const int q0 = qt * 128;

    __shared__ u16 K_lds[64 * 72];         // [key][feat], stride 72
    __shared__ u16 V_lds[64 * 72];         // [feat][key], stride 72
    __shared__ u16 P_lds[4 * 32 * 72];     // per-wave [qrow][key], stride 72

    const int tid = threadIdx.x;
    const int wave = tid >> 6, lane = tid & 63;
    const int l15 = lane & 15, quad = lane >> 4;
    u16* Pw = P_lds + wave * (32 * 72);

    const int w0 = q0 + wave * 32;         // wave's first q-row

    // Q fragments: 2 m-tiles x 2 k-steps (pre-scaled by cs in GEMM1)
    s16x8 qf[2][2];
    #pragma unroll
    for (int mi = 0; mi < 2; ++mi) {
        const size_t rowQ = (size_t)(b * T_ + w0 + mi * 16 + l15) * TWO_D + h * HD_;
        qf[mi][0] = load8(qk + rowQ + quad * 8);
        qf[mi][1] = load8(qk + rowQ + 32 + quad * 8);
    }

    f32x4 o[2][4] = {};
    f32x4 osum[2] = {};

    s16x8 ones;
    #pragma unroll
    for (int j = 0; j < 8; ++j) ones[j] = (short)0x3F80;   // bf16 1.0

    // staging: thread covers K rows r0,r0+32 and V feats r0,r0+32, 16B each
    const int r0 = tid >> 3;               // 0..31
    const int s0 = (tid & 7) * 8;          // u16 offset of 16B chunk
    const u16* Kg0 = qk + (size_t)(b * T_ + r0)      * TWO_D + D_ + h * HD_ + s0;
    const u16* Kg1 = qk + (size_t)(b * T_ + r0 + 32) * TWO_D + D_ + h * HD_ + s0;
    const u16* Vg0 = vt + (size_t)(bh * HD_ + r0)      * T_ + s0;
    const u16* Vg1 = vt + (size_t)(bh * HD_ + r0 + 32) * T_ + s0;

    // prefetch tile 0
    s16x8 pk0 = load8(Kg0);
    s16x8 pk1 = load8(Kg1);
    s16x8 pv0 = load8(Vg0);
    s16x8 pv1 = load8(Vg1);

    const int nkt = 2 * qt + 2;
    for (int kt = 0; kt < nkt; ++kt) {
        const int kbase = kt * 64;
        __syncthreads();                   // prior tile's LDS reads done
        *reinterpret_cast<s16x8*>(&K_lds[r0 * 72 + s0])        = pk0;
        *reinterpret_cast<s16x8*>(&K_lds[(r0 + 32) * 72 + s0]) = pk1;
        *reinterpret_cast<s16x8*>(&V_lds[r0 * 72 + s0])        = pv0;
        *reinterpret_cast<s16x8*>(&V_lds[(r0 + 32) * 72 + s0]) = pv1;
        __syncthreads();

        if (kt + 1 < nkt) {                // prefetch next tile (latency
            const int nb = kbase + 64;     //  hidden under this tile's math)
            pk0 = load8(Kg0 + (size_t)nb * TWO_D);
            pk1 = load8(Kg1 + (size_t)nb * TWO_D);
            pv0 = load8(Vg0 + nb);
            pv1 = load8(Vg1 + nb);
        }

        if (kbase <= w0 + 31) {            // wave has unmasked work here
            // S^T = K Q^T : D[m=key][n=qrow]; kf as A, qf as B (same regs)
            f32x4 st[2][4];
            #pragma unroll
            for (int n = 0; n < 4; ++n) {
                const s16x8 kf0 = *reinterpret_cast<const s16x8*>(
                    &K_lds[(n * 16 + l15) * 72 + quad * 8]);
                const s16x8 kf1 = *reinterpret_cast<const s16x8*>(
                    &K_lds[(n * 16 + l15) * 72 + 32 + quad * 8]);
                #pragma unroll
                for (int mi = 0; mi < 2; ++mi) {
                    f32x4 t = {};
                    t = __builtin_amdgcn_mfma_f32_16x16x32_bf16(kf0, qf[mi][0], t, 0, 0, 0);
                    t = __builtin_amdgcn_mfma_f32_16x16x32_bf16(kf1, qf[mi][1], t, 0, 0, 0);
                    st[mi][n] = t;
                }
            }

            // P = exp2(S^T): lane holds keys kbase+n*16+quad*4+{0..3} for
            // qrow w0+mi*16+l15 -> pack 4 bf16, single b64 LDS write.
            const bool diag = (kbase + 63 > w0);
            #pragma unroll
            for (int mi = 0; mi < 2; ++mi) {
                const int qr = w0 + mi * 16 + l15;
                #pragma unroll
                for (int n = 0; n < 4; ++n) {
                    const int kb = kbase + n * 16 + quad * 4;
                    u16x4 pk;
                    #pragma unroll
                    for (int r = 0; r < 4; ++r)
                        pk[r] = bftrunc(exp2f(st[mi][n][r]));
                    if (diag) {
                        #pragma unroll
                        for (int r = 0; r < 4; ++r)
                            if (kb + r > qr) pk[r] = 0;
                    }
                    *reinterpret_cast<u16x4*>(
                        &Pw[(mi * 16 + l15) * 72 + n * 16 + quad * 4]) = pk;
                }
            }

            // O += P V ; rowsum += P * ones (same-wave P write->read; the
            // compiler inserts the lgkmcnt wait -- m120-verified pattern)
            #pragma unroll
            for (int ks = 0; ks < 2; ++ks) {
                s16x8 pa[2];
                #pragma unroll
                for (int mi = 0; mi < 2; ++mi) {
                    pa[mi] = *reinterpret_cast<const s16x8*>(
                        &Pw[(mi * 16 + l15) * 72 + ks * 32 + quad * 8]);
                    osum[mi] = __builtin_amdgcn_mfma_f32_16x16x32_bf16(
                        pa[mi], ones, osum[mi], 0, 0, 0);
                }
                #pragma unroll
                for (int n4 = 0; n4 < 4; ++n4) {
                    const s16x8 vb = *reinterpret_cast<const s16x8*>(
                        &V_lds[(n4 * 16 + l15) * 72 + ks * 32 + quad * 8]);
                    #pragma unroll
                    for (int mi = 0; mi < 2; ++mi)
                        o[mi][n4] = __builtin_amdgcn_mfma_f32_16x16x32_bf16(
                            pa[mi], vb, o[mi][n4], 0, 0, 0);
                }
            }
        }
    }

    #pragma unroll
    for (int mi = 0; mi < 2; ++mi)
        #pragma unroll
        for (int r = 0; r < 4; ++r) {
            const float inv = 1.0f / osum[mi][r];
            const size_t rowO = (size_t)(b * T_ + w0 + mi * 16 + quad * 4 + r) * D_ + h * HD_;
            #pragma unroll
            for (int n4 = 0; n4 < 4; ++n4)
                out[rowO + n4 * 16 + l15] = f2bf(o[mi][n4][r] * inv);
        }
}

// ---------------------------------------------------------------------------
extern "C" void kernel_launch(void* const* d_in, const int* in_sizes, int n_in,
                              void* d_out, int out_size, void* d_ws, size_t ws_size,
                              hipStream_t stream)
{
    const float* x     = (const float*)d_in[0];  // [B,T,D]  fp32
    const float* Wqkv  = (const float*)d_in[1];  // [3D,D]   fp32
    const float* Wproj = (const float*)d_in[2];  // [D,D]    fp32
    const float* bproj = (const float*)d_in[3];  // [D]      fp32
    float* out = (float*)d_out;                  // [B,T,D]  fp32

    const int M = B_ * T_;
    const float cs = 0.18033688011f;             // (1/sqrt(64)) * log2(e)

    // Workspace (bf16 = u16). Total 88 MB, no aliasing.
    u16* xb    = (u16*)d_ws;                              // [M, D]       16 MB
    u16* wqkvb = xb    + (size_t)M * D_;                  // [3D, D]       6 MB
    u16* wprob = wqkvb + (size_t)THREE_D * D_;            // [D, D]        2 MB
    u16* qk    = wprob + (size_t)D_ * D_;                 // [M, 2D]      32 MB
    u16* vtb   = qk    + (size_t)M * TWO_D;               // [B*H*64, T]  16 MB
    u16* attn  = vtb   + (size_t)B_ * H_ * HD_ * T_;      // [M, D]       16 MB

    // 0) fp32 -> bf16 converts
    {
        int n;
        n = M * D_;
        cvt_f32_bf16<<<dim3((n / 4 + 255) / 256), 256, 0, stream>>>(x, xb, n);
        n = THREE_D * D_;
        cvt_f32_bf16<<<dim3((n / 4 + 255) / 256), 256, 0, stream>>>(Wqkv, wqkvb, n);
        n = D_ * D_;
        cvt_f32_bf16<<<dim3((n / 4 + 255) / 256), 256, 0, stream>>>(Wproj, wprob, n);
    }

    // 1) qkv GEMM (256^2 deep-cover pipeline): Q*cs and K -> qk[M,2D]; V -> vt
    gemm256_qkv<<<dim3((M / 256) * (THREE_D / 256)), 512, 0, stream>>>(
        xb, wqkvb, qk, vtb, cs, M, THREE_D, D_, D_, D_);

    // 2) causal flash attention (bf16 out)
    flash_attn6<<<dim3(B_ * H_ * (T_ / 128)), 256, 0, stream>>>(qk, vtb, attn);

    // 3) out = attn @ Wproj^T + bproj   (fp32 out)
    gemm_bt128<0><<<dim3((M / 128) * (D_ / 128)), 256, 0, stream>>>(
        attn, wprob, out, bproj, M, D_, D_, D_, D_, D_, 1.0f, nullptr);
}

// Round 7
// 255.666 us; speedup vs baseline: 1.0937x; 1.0937x over previous
//
#include <hip/hip_runtime.h>
#include <hip/hip_bf16.h>

// Problem constants (fixed by the reference)
#define B_  4
#define T_  2048
#define D_  1024
#define H_  16
#define HD_ 64
#define THREE_D (3 * D_)
#define TWO_D   (2 * D_)

typedef short s16x8 __attribute__((ext_vector_type(8)));   // 8 bf16 (4 VGPRs)
typedef float f32x4 __attribute__((ext_vector_type(4)));   // MFMA C/D frag
typedef unsigned short u16;
typedef unsigned short u16x4 __attribute__((ext_vector_type(4)));

static __device__ __forceinline__ s16x8 load8(const u16* p) {
    return *reinterpret_cast<const s16x8*>(p);
}
static __device__ __forceinline__ u16 f2bf(float f) {
    __hip_bfloat16 h = __float2bfloat16(f);
    return *reinterpret_cast<u16*>(&h);
}
// truncating fp32->bf16 (1 shift). P>=0 and osum uses the same truncated
// values, so the avg -0.2% bias cancels in the softmax normalization.
static __device__ __forceinline__ u16 bftrunc(float f) {
    unsigned u; __builtin_memcpy(&u, &f, 4); return (u16)(u >> 16);
}

// global -> LDS direct DMA, 16B per lane (m97 ladder step: 517 -> 874 TF)
static __device__ __forceinline__ void gload_lds16(const u16* g, u16* l) {
#if __has_builtin(__builtin_amdgcn_global_load_lds)
    __builtin_amdgcn_global_load_lds(
        (__attribute__((address_space(1))) void*)g,
        (__attribute__((address_space(3))) void*)l, 16, 0, 0);
#else
    *reinterpret_cast<s16x8*>(l) = load8(g);
#endif
}

// ---------------------------------------------------------------------------
// fp32 -> bf16 convert (RNE), 4 elements/thread, 3 buffers in ONE launch
// (saves 2 kernel-launch gaps vs separate cvt calls).
// ---------------------------------------------------------------------------
__global__ __launch_bounds__(256) void cvt3_f32_bf16(
    const float* __restrict__ a, u16* __restrict__ oa, int na,
    const float* __restrict__ bsrc, u16* __restrict__ ob, int nb,
    const float* __restrict__ c, u16* __restrict__ oc, int nc)
{
    int i = (blockIdx.x * 256 + threadIdx.x) * 4;
    const float* s; u16* d;
    if (i < na)                { s = a;    d = oa; }
    else if ((i -= na) < nb)   { s = bsrc; d = ob; }
    else if ((i -= nb) < nc)   { s = c;    d = oc; }
    else return;
    const float4 f = *reinterpret_cast<const float4*>(s + i);
    u16x4 r;
    r.x = f2bf(f.x); r.y = f2bf(f.y); r.z = f2bf(f.z); r.w = f2bf(f.w);
    *reinterpret_cast<u16x4*>(d + i) = r;
}

// ---------------------------------------------------------------------------
// m97-style GEMM, BK=64 as two 32-wide panels. C = A @ Bm^T.  (Proven: QKV
// ~71us, both 256^2 replacements lost -- 85.5 and 94.9us -- so this stays.)
// MODE 0: fp32 out + fp32 bias (projection GEMM).
// MODE 1: QKV GEMM. N=3072. Cols [0,1024) -> Q (scaled by qsc, bf16 into
//         qk[M,2048]); [1024,2048) -> K (bf16 into qk); [2048,3072) -> V,
//         written DIRECTLY TRANSPOSED into vt[(b*16+h)*64+f][T] as packed
//         b64 (4 C-rows = 4 consecutive t).
// ---------------------------------------------------------------------------
template<int MODE>
__global__ __launch_bounds__(256) void gemm_bt128(
    const u16* __restrict__ A,
    const u16* __restrict__ Bm,
    void* __restrict__ Cv,
    const float* __restrict__ bias,
    int M, int N, int K, int lda, int ldb, int ldc,
    float qsc, u16* __restrict__ vt)
{
    const int ntiles = N >> 7;
    const int mt = blockIdx.x / ntiles;
    const int nt = blockIdx.x % ntiles;
    const int m0 = mt * 128, n0 = nt * 128;
    const int tid  = threadIdx.x;
    const int lane = tid & 63;
    const int l15  = lane & 15;
    const int quad = lane >> 4;
    const int wave = tid >> 6;
    const int wm = (wave >> 1) * 64;   // wave m-offset in tile
    const int wn = (wave & 1) * 64;    // wave n-offset in tile

    __shared__ u16 A_sh[2][128 * 32];  // [panel][row*32 + k], linear chunks
    __shared__ u16 B_sh[2][128 * 32];

    f32x4 acc[4][4] = {};

    // staging per panel: 512 chunks of 16B; thread t handles chunks t, t+256
    const int c0 = tid, c1 = tid + 256;
    const int ar0 = c0 >> 2, as0 = (c0 & 3) * 8;
    const int ar1 = c1 >> 2, as1 = (c1 & 3) * 8;
    const u16* Ag0 = A  + (size_t)(m0 + ar0) * lda + as0;
    const u16* Ag1 = A  + (size_t)(m0 + ar1) * lda + as1;
    const u16* Bg0 = Bm + (size_t)(n0 + ar0) * ldb + as0;
    const u16* Bg1 = Bm + (size_t)(n0 + ar1) * ldb + as1;

    for (int k0 = 0; k0 < K; k0 += 64) {
        __syncthreads();                  // prior iteration's LDS reads done
        #pragma unroll
        for (int p = 0; p < 2; ++p) {
            gload_lds16(Ag0 + k0 + p * 32, &A_sh[p][c0 * 8]);
            gload_lds16(Ag1 + k0 + p * 32, &A_sh[p][c1 * 8]);
            gload_lds16(Bg0 + k0 + p * 32, &B_sh[p][c0 * 8]);
            gload_lds16(Bg1 + k0 + p * 32, &B_sh[p][c1 * 8]);
        }
        __syncthreads();                  // drains vmcnt before barrier

        #pragma unroll
        for (int p = 0; p < 2; ++p) {
            s16x8 a[4], b[4];
            #pragma unroll
            for (int i = 0; i < 4; ++i) {
                a[i] = *reinterpret_cast<const s16x8*>(&A_sh[p][(wm + i * 16 + l15) * 32 + quad * 8]);
                b[i] = *reinterpret_cast<const s16x8*>(&B_sh[p][(wn + i * 16 + l15) * 32 + quad * 8]);
            }
            #pragma unroll
            for (int mi = 0; mi < 4; ++mi)
                #pragma unroll
                for (int ni = 0; ni < 4; ++ni)
                    acc[mi][ni] = __builtin_amdgcn_mfma_f32_16x16x32_bf16(
                        a[mi], b[ni], acc[mi][ni], 0, 0, 0);
        }
    }

    // Epilogue. C/D layout: row = quad*4 + r, col = lane&15
    #pragma unroll
    for (int ni = 0; ni < 4; ++ni) {
        const int col = n0 + wn + ni * 16 + l15;
        if (MODE == 0) {
            const float bv = bias ? bias[col] : 0.0f;
            #pragma unroll
            for (int mi = 0; mi < 4; ++mi) {
                const int row = m0 + wm + mi * 16 + quad * 4;
                #pragma unroll
                for (int r = 0; r < 4; ++r)
                    ((float*)Cv)[(size_t)(row + r) * ldc + col] = acc[mi][ni][r] + bv;
            }
        } else {
            if (col < TWO_D) {               // Q (scaled) or K -> qk buffer
                const float sc = (col < D_) ? qsc : 1.0f;
                #pragma unroll
                for (int mi = 0; mi < 4; ++mi) {
                    const int row = m0 + wm + mi * 16 + quad * 4;
                    #pragma unroll
                    for (int r = 0; r < 4; ++r)
                        ((u16*)Cv)[(size_t)(row + r) * ldc + col] = f2bf(acc[mi][ni][r] * sc);
                }
            } else {                         // V -> transposed vt, packed b64
                const int vc = col - TWO_D;  // h*64 + f
                #pragma unroll
                for (int mi = 0; mi < 4; ++mi) {
                    const int row = m0 + wm + mi * 16 + quad * 4;
                    const int bb = row >> 11, t = row & (T_ - 1);
                    u16x4 pk;
                    #pragma unroll
                    for (int r = 0; r < 4; ++r) pk[r] = f2bf(acc[mi][ni][r]);
                    *reinterpret_cast<u16x4*>(
                        vt + ((size_t)(bb * H_ * HD_) + vc) * T_ + t) = pk;
                }
            }
        }
    }
}

// ---------------------------------------------------------------------------
// Causal flash attention v11 = v6 inner body (proven) with Q-TILE 256.
//
// Rationale (v9/v10 PMC): the per-tile structural costs -- K/V staging
// ds_writes, 2 full-drain barriers, prefetch address VALU -- dominate over
// intrinsic work. v6 pays them 272 times per (b,h) (Sum over 16 Q-blocks of
// 2qt+2 tiles) because every 128-row Q-block re-stages all its K/V tiles.
// Q-tile 256 (8 waves x 32 q-rows, 512 threads) pays them 144 times (-47%):
//   - staging: each thread covers ONE 16B chunk of K and one of V
//     (512 x 16B = 8KB = exactly one 64x64 bf16 tile each).
//   - inner tile body (S^T mfma, P pack, PV, rowsum) is v6-VERBATIM.
//   - LDS 55.3KB (K 9.2 + V 9.2 + P 36.9) -> 2 blocks/CU = 16 waves/CU,
//     double v6's residency.
//   - load balance: work ~ qt+1; heavy blocks dispatch FIRST (qt = 7-cls)
//     so the 512-block grid on 256 CUs schedules greedily (LPT).
// ---------------------------------------------------------------------------
__global__ __launch_bounds__(512) void flash_attn11(
    const u16* __restrict__ qk, const u16* __restrict__ vt,
    u16* __restrict__ out)   // [B*T, D] bf16
{
    const int cls = blockIdx.x >> 6;          // 0..7
    const int bh  = blockIdx.x & 63;
    const int qt  = 7 - cls;                  // heaviest first (LPT)
    const int h = bh & 15, b = bh >> 4;
    const int q0 = qt * 256;

    __shared__ u16 K_lds[64 * 72];         // [key][feat], stride 72
    __shared__ u16 V_lds[64 * 72];         // [feat][key], stride 72
    __shared__ u16 P_lds[8 * 32 * 72];     // per-wave [qrow][key], stride 72

    const int tid = threadIdx.x;
    const int wave = tid >> 6, lane = tid & 63;
    const int l15 = lane & 15, quad = lane >> 4;
    u16* Pw = P_lds + wave * (32 * 72);

    const int w0 = q0 + wave * 32;         // wave's first q-row

    // Q fragments: 2 m-tiles x 2 k-steps (pre-scaled by cs in GEMM1)
    s16x8 qf[2][2];
    #pragma unroll
    for (int mi = 0; mi < 2; ++mi) {
        const size_t rowQ = (size_t)(b * T_ + w0 + mi * 16 + l15) * TWO_D + h * HD_;
        qf[mi][0] = load8(qk + rowQ + quad * 8);
        qf[mi][1] = load8(qk + rowQ + 32 + quad * 8);
    }

    f32x4 o[2][4] = {};
    f32x4 osum[2] = {};

    s16x8 ones;
    #pragma unroll
    for (int j = 0; j < 8; ++j) ones[j] = (short)0x3F80;   // bf16 1.0

    // staging: thread covers ONE 16B chunk: K row rk (key), V row rk (feat)
    const int rk = tid >> 3;               // 0..63
    const int s0 = (tid & 7) * 8;          // u16 offset of 16B chunk
    const u16* Kg = qk + (size_t)(b * T_ + rk) * TWO_D + D_ + h * HD_ + s0;
    const u16* Vg = vt + (size_t)(bh * HD_ + rk) * T_ + s0;

    // prefetch tile 0
    s16x8 pk0 = load8(Kg);
    s16x8 pv0 = load8(Vg);

    const int nkt = 4 * qt + 4;
    for (int kt = 0; kt < nkt; ++kt) {
        const int kbase = kt * 64;
        __syncthreads();                   // prior tile's LDS reads done
        *reinterpret_cast<s16x8*>(&K_lds[rk * 72 + s0]) = pk0;
        *reinterpret_cast<s16x8*>(&V_lds[rk * 72 + s0]) = pv0;
        __syncthreads();

        if (kt + 1 < nkt) {                // prefetch next tile (latency
            const int nb = kbase + 64;     //  hidden under this tile's math)
            pk0 = load8(Kg + (size_t)nb * TWO_D);
            pv0 = load8(Vg + nb);
        }

        if (kbase <= w0 + 31) {            // wave has unmasked work here
            // S^T = K Q^T : D[m=key][n=qrow]; kf as A, qf as B (same regs)
            f32x4 st[2][4];
            #pragma unroll
            for (int n = 0; n < 4; ++n) {
                const s16x8 kf0 = *reinterpret_cast<const s16x8*>(
                    &K_lds[(n * 16 + l15) * 72 + quad * 8]);
                const s16x8 kf1 = *reinterpret_cast<const s16x8*>(
                    &K_lds[(n * 16 + l15) * 72 + 32 + quad * 8]);
                #pragma unroll
                for (int mi = 0; mi < 2; ++mi) {
                    f32x4 t = {};
                    t = __builtin_amdgcn_mfma_f32_16x16x32_bf16(kf0, qf[mi][0], t, 0, 0, 0);
                    t = __builtin_amdgcn_mfma_f32_16x16x32_bf16(kf1, qf[mi][1], t, 0, 0, 0);
                    st[mi][n] = t;
                }
            }

            // P = exp2(S^T): lane holds keys kbase+n*16+quad*4+{0..3} for
            // qrow w0+mi*16+l15 -> pack 4 bf16, single b64 LDS write.
            const bool diag = (kbase + 63 > w0);
            #pragma unroll
            for (int mi = 0; mi < 2; ++mi) {
                const int qr = w0 + mi * 16 + l15;
                #pragma unroll
                for (int n = 0; n < 4; ++n) {
                    const int kb = kbase + n * 16 + quad * 4;
                    u16x4 pk;
                    #pragma unroll
                    for (int r = 0; r < 4; ++r)
                        pk[r] = bftrunc(exp2f(st[mi][n][r]));
                    if (diag) {
                        #pragma unroll
                        for (int r = 0; r < 4; ++r)
                            if (kb + r > qr) pk[r] = 0;
                    }
                    *reinterpret_cast<u16x4*>(
                        &Pw[(mi * 16 + l15) * 72 + n * 16 + quad * 4]) = pk;
                }
            }

            // O += P V ; rowsum += P * ones (same-wave P write->read; the
            // compiler inserts the lgkmcnt wait -- m120-verified pattern)
            #pragma unroll
            for (int ks = 0; ks < 2; ++ks) {
                s16x8 pa[2];
                #pragma unroll
                for (int mi = 0; mi < 2; ++mi) {
                    pa[mi] = *reinterpret_cast<const s16x8*>(
                        &Pw[(mi * 16 + l15) * 72 + ks * 32 + quad * 8]);
                    osum[mi] = __builtin_amdgcn_mfma_f32_16x16x32_bf16(
                        pa[mi], ones, osum[mi], 0, 0, 0);
                }
                #pragma unroll
                for (int n4 = 0; n4 < 4; ++n4) {
                    const s16x8 vb = *reinterpret_cast<const s16x8*>(
                        &V_lds[(n4 * 16 + l15) * 72 + ks * 32 + quad * 8]);
                    #pragma unroll
                    for (int mi = 0; mi < 2; ++mi)
                        o[mi][n4] = __builtin_amdgcn_mfma_f32_16x16x32_bf16(
                            pa[mi], vb, o[mi][n4], 0, 0, 0);
                }
            }
        }
    }

    #pragma unroll
    for (int mi = 0; mi < 2; ++mi)
        #pragma unroll
        for (int r = 0; r < 4; ++r) {
            const float inv = 1.0f / osum[mi][r];
            const size_t rowO = (size_t)(b * T_ + w0 + mi * 16 + quad * 4 + r) * D_ + h * HD_;
            #pragma unroll
            for (int n4 = 0; n4 < 4; ++n4)
                out[rowO + n4 * 16 + l15] = f2bf(o[mi][n4][r] * inv);
        }
}

// ---------------------------------------------------------------------------
extern "C" void kernel_launch(void* const* d_in, const int* in_sizes, int n_in,
                              void* d_out, int out_size, void* d_ws, size_t ws_size,
                              hipStream_t stream)
{
    const float* x     = (const float*)d_in[0];  // [B,T,D]  fp32
    const float* Wqkv  = (const float*)d_in[1];  // [3D,D]   fp32
    const float* Wproj = (const float*)d_in[2];  // [D,D]    fp32
    const float* bproj = (const float*)d_in[3];  // [D]      fp32
    float* out = (float*)d_out;                  // [B,T,D]  fp32

    const int M = B_ * T_;
    const float cs = 0.18033688011f;             // (1/sqrt(64)) * log2(e)

    // Workspace (bf16 = u16). Total 88 MB, no aliasing.
    u16* xb    = (u16*)d_ws;                              // [M, D]       16 MB
    u16* wqkvb = xb    + (size_t)M * D_;                  // [3D, D]       6 MB
    u16* wprob = wqkvb + (size_t)THREE_D * D_;            // [D, D]        2 MB
    u16* qk    = wprob + (size_t)D_ * D_;                 // [M, 2D]      32 MB
    u16* vtb   = qk    + (size_t)M * TWO_D;               // [B*H*64, T]  16 MB
    u16* attn  = vtb   + (size_t)B_ * H_ * HD_ * T_;      // [M, D]       16 MB

    // 0) fp32 -> bf16 converts (single launch, 3 segments)
    {
        const int na = M * D_, nb = THREE_D * D_, nc = D_ * D_;
        const int total = na + nb + nc;
        cvt3_f32_bf16<<<dim3((total / 4 + 255) / 256), 256, 0, stream>>>(
            x, xb, na, Wqkv, wqkvb, nb, Wproj, wprob, nc);
    }

    // 1) qkv GEMM: Q (scaled by cs) and K -> qk[M,2D]; V -> vt transposed
    gemm_bt128<1><<<dim3((M / 128) * (THREE_D / 128)), 256, 0, stream>>>(
        xb, wqkvb, qk, nullptr, M, THREE_D, D_, D_, D_, TWO_D, cs, vtb);

    // 2) causal flash attention (bf16 out), Q-tile 256, 8 waves
    flash_attn11<<<dim3(B_ * H_ * (T_ / 256)), 512, 0, stream>>>(qk, vtb, attn);

    // 3) out = attn @ Wproj^T + bproj   (fp32 out)
    gemm_bt128<0><<<dim3((M / 128) * (D_ / 128)), 256, 0, stream>>>(
        attn, wprob, out, bproj, M, D_, D_, D_, D_, D_, 1.0f, nullptr);
}

// Round 8
// 243.707 us; speedup vs baseline: 1.1473x; 1.0491x over previous
//
#include <hip/hip_runtime.h>
#include <hip/hip_bf16.h>

// Problem constants (fixed by the reference)
#define B_  4
#define T_  2048
#define D_  1024
#define H_  16
#define HD_ 64
#define THREE_D (3 * D_)
#define TWO_D   (2 * D_)

typedef short s16x8 __attribute__((ext_vector_type(8)));   // 8 bf16 (4 VGPRs)
typedef float f32x4 __attribute__((ext_vector_type(4)));   // MFMA C/D frag
typedef unsigned short u16;
typedef unsigned short u16x4 __attribute__((ext_vector_type(4)));

static __device__ __forceinline__ s16x8 load8(const u16* p) {
    return *reinterpret_cast<const s16x8*>(p);
}
static __device__ __forceinline__ u16 f2bf(float f) {
    __hip_bfloat16 h = __float2bfloat16(f);
    return *reinterpret_cast<u16*>(&h);
}
// truncating fp32->bf16 (1 shift). P>=0 and osum uses the same truncated
// values, so the avg -0.2% bias cancels in the softmax normalization.
static __device__ __forceinline__ u16 bftrunc(float f) {
    unsigned u; __builtin_memcpy(&u, &f, 4); return (u16)(u >> 16);
}

// global -> LDS direct DMA, 16B per lane (m97 ladder step: 517 -> 874 TF)
static __device__ __forceinline__ void gload_lds16(const u16* g, u16* l) {
#if __has_builtin(__builtin_amdgcn_global_load_lds)
    __builtin_amdgcn_global_load_lds(
        (__attribute__((address_space(1))) void*)g,
        (__attribute__((address_space(3))) void*)l, 16, 0, 0);
#else
    *reinterpret_cast<s16x8*>(l) = load8(g);
#endif
}

// ---------------------------------------------------------------------------
// fp32 -> bf16 convert (RNE), 4 elements/thread, 3 buffers in ONE launch.
// ---------------------------------------------------------------------------
__global__ __launch_bounds__(256) void cvt3_f32_bf16(
    const float* __restrict__ a, u16* __restrict__ oa, int na,
    const float* __restrict__ bsrc, u16* __restrict__ ob, int nb,
    const float* __restrict__ c, u16* __restrict__ oc, int nc)
{
    int i = (blockIdx.x * 256 + threadIdx.x) * 4;
    const float* s; u16* d;
    if (i < na)                { s = a;    d = oa; }
    else if ((i -= na) < nb)   { s = bsrc; d = ob; }
    else if ((i -= nb) < nc)   { s = c;    d = oc; }
    else return;
    const float4 f = *reinterpret_cast<const float4*>(s + i);
    u16x4 r;
    r.x = f2bf(f.x); r.y = f2bf(f.y); r.z = f2bf(f.z); r.w = f2bf(f.w);
    *reinterpret_cast<u16x4*>(d + i) = r;
}

// ---------------------------------------------------------------------------
// m97-style GEMM, BK=64 as two 32-wide panels. C = A @ Bm^T.
// NEW: bijective XCD-chunked block swizzle (T1). Each XCD (bid&7) owns a
// contiguous mt-range (mtpc=cpx/ntiles rows of tiles); within the chunk,
// mt-minor/nt-major order keeps the XCD's A-slice (mtpc*256KB = 2MB)
// L2-resident while B panels stream 256KB at a time. Requires nwg%8==0 and
// cpx%ntiles==0 -- both hold for our launches (1536/24, 512/8).
// MODE 0: fp32 out + fp32 bias (projection GEMM).
// MODE 1: QKV GEMM. N=3072. Cols [0,1024) -> Q (scaled by qsc, bf16 into
//         qk[M,2048]); [1024,2048) -> K (bf16 into qk); [2048,3072) -> V,
//         written DIRECTLY TRANSPOSED into vt[(b*16+h)*64+f][T].
// ---------------------------------------------------------------------------
template<int MODE>
__global__ __launch_bounds__(256) void gemm_bt128(
    const u16* __restrict__ A,
    const u16* __restrict__ Bm,
    void* __restrict__ Cv,
    const float* __restrict__ bias,
    int M, int N, int K, int lda, int ldb, int ldc,
    float qsc, u16* __restrict__ vt)
{
    const int ntiles = N >> 7;
    const int nwg  = (M >> 7) * ntiles;
    const int cpx  = nwg >> 3;            // blocks per XCD chunk
    const int mtpc = cpx / ntiles;        // mt rows per chunk (8 here)
    const int xcd  = (int)blockIdx.x & 7;
    const int lc   = (int)blockIdx.x >> 3;
    const int nt = lc / mtpc;
    const int mt = xcd * mtpc + (lc % mtpc);
    const int m0 = mt * 128, n0 = nt * 128;
    const int tid  = threadIdx.x;
    const int lane = tid & 63;
    const int l15  = lane & 15;
    const int quad = lane >> 4;
    const int wave = tid >> 6;
    const int wm = (wave >> 1) * 64;   // wave m-offset in tile
    const int wn = (wave & 1) * 64;    // wave n-offset in tile

    __shared__ u16 A_sh[2][128 * 32];  // [panel][row*32 + k], linear chunks
    __shared__ u16 B_sh[2][128 * 32];

    f32x4 acc[4][4] = {};

    // staging per panel: 512 chunks of 16B; thread t handles chunks t, t+256
    const int c0 = tid, c1 = tid + 256;
    const int ar0 = c0 >> 2, as0 = (c0 & 3) * 8;
    const int ar1 = c1 >> 2, as1 = (c1 & 3) * 8;
    const u16* Ag0 = A  + (size_t)(m0 + ar0) * lda + as0;
    const u16* Ag1 = A  + (size_t)(m0 + ar1) * lda + as1;
    const u16* Bg0 = Bm + (size_t)(n0 + ar0) * ldb + as0;
    const u16* Bg1 = Bm + (size_t)(n0 + ar1) * ldb + as1;

    for (int k0 = 0; k0 < K; k0 += 64) {
        __syncthreads();                  // prior iteration's LDS reads done
        #pragma unroll
        for (int p = 0; p < 2; ++p) {
            gload_lds16(Ag0 + k0 + p * 32, &A_sh[p][c0 * 8]);
            gload_lds16(Ag1 + k0 + p * 32, &A_sh[p][c1 * 8]);
            gload_lds16(Bg0 + k0 + p * 32, &B_sh[p][c0 * 8]);
            gload_lds16(Bg1 + k0 + p * 32, &B_sh[p][c1 * 8]);
        }
        __syncthreads();                  // drains vmcnt before barrier

        #pragma unroll
        for (int p = 0; p < 2; ++p) {
            s16x8 a[4], b[4];
            #pragma unroll
            for (int i = 0; i < 4; ++i) {
                a[i] = *reinterpret_cast<const s16x8*>(&A_sh[p][(wm + i * 16 + l15) * 32 + quad * 8]);
                b[i] = *reinterpret_cast<const s16x8*>(&B_sh[p][(wn + i * 16 + l15) * 32 + quad * 8]);
            }
            #pragma unroll
            for (int mi = 0; mi < 4; ++mi)
                #pragma unroll
                for (int ni = 0; ni < 4; ++ni)
                    acc[mi][ni] = __builtin_amdgcn_mfma_f32_16x16x32_bf16(
                        a[mi], b[ni], acc[mi][ni], 0, 0, 0);
        }
    }

    // Epilogue. C/D layout: row = quad*4 + r, col = lane&15
    #pragma unroll
    for (int ni = 0; ni < 4; ++ni) {
        const int col = n0 + wn + ni * 16 + l15;
        if (MODE == 0) {
            const float bv = bias ? bias[col] : 0.0f;
            #pragma unroll
            for (int mi = 0; mi < 4; ++mi) {
                const int row = m0 + wm + mi * 16 + quad * 4;
                #pragma unroll
                for (int r = 0; r < 4; ++r)
                    ((float*)Cv)[(size_t)(row + r) * ldc + col] = acc[mi][ni][r] + bv;
            }
        } else {
            if (col < TWO_D) {               // Q (scaled) or K -> qk buffer
                const float sc = (col < D_) ? qsc : 1.0f;
                #pragma unroll
                for (int mi = 0; mi < 4; ++mi) {
                    const int row = m0 + wm + mi * 16 + quad * 4;
                    #pragma unroll
                    for (int r = 0; r < 4; ++r)
                        ((u16*)Cv)[(size_t)(row + r) * ldc + col] = f2bf(acc[mi][ni][r] * sc);
                }
            } else {                         // V -> transposed vt, packed b64
                const int vc = col - TWO_D;  // h*64 + f
                #pragma unroll
                for (int mi = 0; mi < 4; ++mi) {
                    const int row = m0 + wm + mi * 16 + quad * 4;
                    const int bb = row >> 11, t = row & (T_ - 1);
                    u16x4 pk;
                    #pragma unroll
                    for (int r = 0; r < 4; ++r) pk[r] = f2bf(acc[mi][ni][r]);
                    *reinterpret_cast<u16x4*>(
                        vt + ((size_t)(bb * H_ * HD_) + vc) * T_ + t) = pk;
                }
            }
        }
    }
}

// ---------------------------------------------------------------------------
// Causal flash attention v6s = v6 (proven 75.4us) with K/V LDS XOR-swizzle.
//
// v6's K/V used stride-72 padding -> residual 2-way conflicts on every
// staging write and frag read (v9 ablation: ~6.5M of the 7.57M conflict
// cycles are K/V, not P). Since v6 stages via the REGISTER path (ds_write
// address is free -- no DMA linearity constraint), switch to unpadded
// [64][64] rows with the proven 3-bit involution: 16B-chunk ^= (row&7),
// applied on write AND read (round-6 GEMM measured ZERO conflicts with the
// identical pattern: rows vary by l15, chunk by quad). P_lds keeps its
// stride-72 layout (b64-granular writes; ~1.1M residual, small).
// Everything else is v6-verbatim: 4 waves x 32 q-rows, KV-tile 64, register
// prefetch, S^T via mfma(A=kf,B=qf), b64 P pack, ones-MFMA rowsum, qmap.
// ---------------------------------------------------------------------------
__global__ __launch_bounds__(256) void flash_attn6s(
    const u16* __restrict__ qk, const u16* __restrict__ vt,
    u16* __restrict__ out)   // [B*T, D] bf16
{
    const int cls = blockIdx.x >> 6;          // 0..15
    const int bh  = blockIdx.x & 63;
    const int qmap[16] = {15,14,13,12, 8,9,10,11, 7,6,5,4, 0,1,2,3};
    const int qt = qmap[cls];
    const int h = bh & 15, b = bh >> 4;
    const int q0 = qt * 128;

    __shared__ u16 K_lds[64 * 64];         // [key][feat], chunk^=(row&7)
    __shared__ u16 V_lds[64 * 64];         // [feat][key], chunk^=(row&7)
    __shared__ u16 P_lds[4 * 32 * 72];     // per-wave [qrow][key], stride 72

    const int tid = threadIdx.x;
    const int wave = tid >> 6, lane = tid & 63;
    const int l15 = lane & 15, quad = lane >> 4;
    u16* Pw = P_lds + wave * (32 * 72);

    const int w0 = q0 + wave * 32;         // wave's first q-row

    // Q fragments: 2 m-tiles x 2 k-steps (pre-scaled by cs in GEMM1)
    s16x8 qf[2][2];
    #pragma unroll
    for (int mi = 0; mi < 2; ++mi) {
        const size_t rowQ = (size_t)(b * T_ + w0 + mi * 16 + l15) * TWO_D + h * HD_;
        qf[mi][0] = load8(qk + rowQ + quad * 8);
        qf[mi][1] = load8(qk + rowQ + 32 + quad * 8);
    }

    f32x4 o[2][4] = {};
    f32x4 osum[2] = {};

    s16x8 ones;
    #pragma unroll
    for (int j = 0; j < 8; ++j) ones[j] = (short)0x3F80;   // bf16 1.0

    // staging: thread covers K rows r0,r0+32 and V feats r0,r0+32, 16B each.
    // LDS write chunk is XOR-swizzled; (r0+32)&7 == r0&7 so both rows share
    // the same swizzled chunk offset. Global source stays linear.
    const int r0 = tid >> 3;               // 0..31
    const int s0 = (tid & 7) * 8;          // u16 offset of 16B chunk (global)
    const int wsw = (((tid & 7) ^ (r0 & 7)) * 8);   // swizzled LDS chunk
    const u16* Kg0 = qk + (size_t)(b * T_ + r0)      * TWO_D + D_ + h * HD_ + s0;
    const u16* Kg1 = qk + (size_t)(b * T_ + r0 + 32) * TWO_D + D_ + h * HD_ + s0;
    const u16* Vg0 = vt + (size_t)(bh * HD_ + r0)      * T_ + s0;
    const u16* Vg1 = vt + (size_t)(bh * HD_ + r0 + 32) * T_ + s0;

    // prefetch tile 0
    s16x8 pk0 = load8(Kg0);
    s16x8 pk1 = load8(Kg1);
    s16x8 pv0 = load8(Vg0);
    s16x8 pv1 = load8(Vg1);

    // read-side swizzle: frag rows are n*16+l15 -> row&7 == l15&7
    const int rsw = l15 & 7;

    const int nkt = 2 * qt + 2;
    for (int kt = 0; kt < nkt; ++kt) {
        const int kbase = kt * 64;
        __syncthreads();                   // prior tile's LDS reads done
        *reinterpret_cast<s16x8*>(&K_lds[r0 * 64 + wsw])        = pk0;
        *reinterpret_cast<s16x8*>(&K_lds[(r0 + 32) * 64 + wsw]) = pk1;
        *reinterpret_cast<s16x8*>(&V_lds[r0 * 64 + wsw])        = pv0;
        *reinterpret_cast<s16x8*>(&V_lds[(r0 + 32) * 64 + wsw]) = pv1;
        __syncthreads();

        if (kt + 1 < nkt) {                // prefetch next tile (latency
            const int nb = kbase + 64;     //  hidden under this tile's math)
            pk0 = load8(Kg0 + (size_t)nb * TWO_D);
            pk1 = load8(Kg1 + (size_t)nb * TWO_D);
            pv0 = load8(Vg0 + nb);
            pv1 = load8(Vg1 + nb);
        }

        if (kbase <= w0 + 31) {            // wave has unmasked work here
            // S^T = K Q^T : D[m=key][n=qrow]; kf as A, qf as B (same regs)
            f32x4 st[2][4];
            #pragma unroll
            for (int n = 0; n < 4; ++n) {
                const s16x8 kf0 = *reinterpret_cast<const s16x8*>(
                    &K_lds[(n * 16 + l15) * 64 + ((quad ^ rsw) * 8)]);
                const s16x8 kf1 = *reinterpret_cast<const s16x8*>(
                    &K_lds[(n * 16 + l15) * 64 + (((quad ^ 4) ^ rsw) * 8)]);
                #pragma unroll
                for (int mi = 0; mi < 2; ++mi) {
                    f32x4 t = {};
                    t = __builtin_amdgcn_mfma_f32_16x16x32_bf16(kf0, qf[mi][0], t, 0, 0, 0);
                    t = __builtin_amdgcn_mfma_f32_16x16x32_bf16(kf1, qf[mi][1], t, 0, 0, 0);
                    st[mi][n] = t;
                }
            }

            // P = exp2(S^T): lane holds keys kbase+n*16+quad*4+{0..3} for
            // qrow w0+mi*16+l15 -> pack 4 bf16, single b64 LDS write.
            const bool diag = (kbase + 63 > w0);
            #pragma unroll
            for (int mi = 0; mi < 2; ++mi) {
                const int qr = w0 + mi * 16 + l15;
                #pragma unroll
                for (int n = 0; n < 4; ++n) {
                    const int kb = kbase + n * 16 + quad * 4;
                    u16x4 pk;
                    #pragma unroll
                    for (int r = 0; r < 4; ++r)
                        pk[r] = bftrunc(exp2f(st[mi][n][r]));
                    if (diag) {
                        #pragma unroll
                        for (int r = 0; r < 4; ++r)
                            if (kb + r > qr) pk[r] = 0;
                    }
                    *reinterpret_cast<u16x4*>(
                        &Pw[(mi * 16 + l15) * 72 + n * 16 + quad * 4]) = pk;
                }
            }

            // O += P V ; rowsum += P * ones (same-wave P write->read; the
            // compiler inserts the lgkmcnt wait -- m120-verified pattern)
            #pragma unroll
            for (int ks = 0; ks < 2; ++ks) {
                s16x8 pa[2];
                #pragma unroll
                for (int mi = 0; mi < 2; ++mi) {
                    pa[mi] = *reinterpret_cast<const s16x8*>(
                        &Pw[(mi * 16 + l15) * 72 + ks * 32 + quad * 8]);
                    osum[mi] = __builtin_amdgcn_mfma_f32_16x16x32_bf16(
                        pa[mi], ones, osum[mi], 0, 0, 0);
                }
                #pragma unroll
                for (int n4 = 0; n4 < 4; ++n4) {
                    const s16x8 vb = *reinterpret_cast<const s16x8*>(
                        &V_lds[(n4 * 16 + l15) * 64 + (((ks * 4 + quad) ^ rsw) * 8)]);
                    #pragma unroll
                    for (int mi = 0; mi < 2; ++mi)
                        o[mi][n4] = __builtin_amdgcn_mfma_f32_16x16x32_bf16(
                            pa[mi], vb, o[mi][n4], 0, 0, 0);
                }
            }
        }
    }

    #pragma unroll
    for (int mi = 0; mi < 2; ++mi)
        #pragma unroll
        for (int r = 0; r < 4; ++r) {
            const float inv = 1.0f / osum[mi][r];
            const size_t rowO = (size_t)(b * T_ + w0 + mi * 16 + quad * 4 + r) * D_ + h * HD_;
            #pragma unroll
            for (int n4 = 0; n4 < 4; ++n4)
                out[rowO + n4 * 16 + l15] = f2bf(o[mi][n4][r] * inv);
        }
}

// ---------------------------------------------------------------------------
extern "C" void kernel_launch(void* const* d_in, const int* in_sizes, int n_in,
                              void* d_out, int out_size, void* d_ws, size_t ws_size,
                              hipStream_t stream)
{
    const float* x     = (const float*)d_in[0];  // [B,T,D]  fp32
    const float* Wqkv  = (const float*)d_in[1];  // [3D,D]   fp32
    const float* Wproj = (const float*)d_in[2];  // [D,D]    fp32
    const float* bproj = (const float*)d_in[3];  // [D]      fp32
    float* out = (float*)d_out;                  // [B,T,D]  fp32

    const int M = B_ * T_;
    const float cs = 0.18033688011f;             // (1/sqrt(64)) * log2(e)

    // Workspace (bf16 = u16). Total 88 MB, no aliasing.
    u16* xb    = (u16*)d_ws;                              // [M, D]       16 MB
    u16* wqkvb = xb    + (size_t)M * D_;                  // [3D, D]       6 MB
    u16* wprob = wqkvb + (size_t)THREE_D * D_;            // [D, D]        2 MB
    u16* qk    = wprob + (size_t)D_ * D_;                 // [M, 2D]      32 MB
    u16* vtb   = qk    + (size_t)M * TWO_D;               // [B*H*64, T]  16 MB
    u16* attn  = vtb   + (size_t)B_ * H_ * HD_ * T_;      // [M, D]       16 MB

    // 0) fp32 -> bf16 converts (single launch, 3 segments)
    {
        const int na = M * D_, nb = THREE_D * D_, nc = D_ * D_;
        const int total = na + nb + nc;
        cvt3_f32_bf16<<<dim3((total / 4 + 255) / 256), 256, 0, stream>>>(
            x, xb, na, Wqkv, wqkvb, nb, Wproj, wprob, nc);
    }

    // 1) qkv GEMM: Q (scaled by cs) and K -> qk[M,2D]; V -> vt transposed
    gemm_bt128<1><<<dim3((M / 128) * (THREE_D / 128)), 256, 0, stream>>>(
        xb, wqkvb, qk, nullptr, M, THREE_D, D_, D_, D_, TWO_D, cs, vtb);

    // 2) causal flash attention (bf16 out), Q-tile 128, 4 waves (v6 grid)
    flash_attn6s<<<dim3(B_ * H_ * (T_ / 128)), 256, 0, stream>>>(qk, vtb, attn);

    // 3) out = attn @ Wproj^T + bproj   (fp32 out)
    gemm_bt128<0><<<dim3((M / 128) * (D_ / 128)), 256, 0, stream>>>(
        attn, wprob, out, bproj, M, D_, D_, D_, D_, D_, 1.0f, nullptr);
}

// Round 9
// 238.926 us; speedup vs baseline: 1.1703x; 1.0200x over previous
//
#include <hip/hip_runtime.h>
#include <hip/hip_bf16.h>

// Problem constants (fixed by the reference)
#define B_  4
#define T_  2048
#define D_  1024
#define H_  16
#define HD_ 64
#define THREE_D (3 * D_)
#define TWO_D   (2 * D_)

typedef short s16x8 __attribute__((ext_vector_type(8)));   // 8 bf16 (4 VGPRs)
typedef float f32x4 __attribute__((ext_vector_type(4)));   // MFMA C/D frag
typedef unsigned short u16;
typedef unsigned short u16x4 __attribute__((ext_vector_type(4)));
typedef unsigned int u32x2 __attribute__((ext_vector_type(2)));

static __device__ __forceinline__ s16x8 load8(const u16* p) {
    return *reinterpret_cast<const s16x8*>(p);
}
static __device__ __forceinline__ u16 f2bf(float f) {
    __hip_bfloat16 h = __float2bfloat16(f);
    return *reinterpret_cast<u16*>(&h);
}
// truncating fp32->bf16 (1 shift). P>=0 and osum uses the same truncated
// values, so the avg -0.2% bias cancels in the softmax normalization.
static __device__ __forceinline__ u16 bftrunc(float f) {
    unsigned u; __builtin_memcpy(&u, &f, 4); return (u16)(u >> 16);
}
// truncating pack: (trunc_bf16(hi) << 16) | trunc_bf16(lo), ONE v_perm_b32.
// Correctness-proven in v10 (passed, absmax 0.0176).
static __device__ __forceinline__ unsigned pktrunc(float lo, float hi) {
#if __has_builtin(__builtin_amdgcn_perm)
    // combo {src0:src1} bytes 7..0; sel 0x07060302 -> dst = hi[3:2]:lo[3:2]
    return __builtin_amdgcn_perm(__builtin_bit_cast(unsigned, hi),
                                 __builtin_bit_cast(unsigned, lo),
                                 0x07060302u);
#else
    return (__builtin_bit_cast(unsigned, hi) & 0xFFFF0000u) |
           (__builtin_bit_cast(unsigned, lo) >> 16);
#endif
}
// RAW-HW exp2: v_exp_f32 (1 trans-VALU op, ~1 ulp). exp2f without
// fast-math lowers to OCML __ocml_exp2_f32 (~15-20 VALU ops/element) --
// measured as ~1100 of the ~1500 VALU cyc/tile in flash_attn (r8 PMC
// arithmetic: 0.58*74.2us*2.4GHz / 68 wave-tiles = 1514 cyc; raw-exp
// inventory = ~400). Plain VALU ops are scoreboarded on CDNA, so the asm
// fallback has no hazard issue (unlike MFMA asm, v8 lesson).
static __device__ __forceinline__ float fast_exp2(float x) {
#if __has_builtin(__builtin_amdgcn_exp2f)
    return __builtin_amdgcn_exp2f(x);
#else
    float r;
    asm("v_exp_f32 %0, %1" : "=v"(r) : "v"(x));
    return r;
#endif
}

// global -> LDS direct DMA, 16B per lane (m97 ladder step: 517 -> 874 TF)
static __device__ __forceinline__ void gload_lds16(const u16* g, u16* l) {
#if __has_builtin(__builtin_amdgcn_global_load_lds)
    __builtin_amdgcn_global_load_lds(
        (__attribute__((address_space(1))) void*)g,
        (__attribute__((address_space(3))) void*)l, 16, 0, 0);
#else
    *reinterpret_cast<s16x8*>(l) = load8(g);
#endif
}

// ---------------------------------------------------------------------------
// fp32 -> bf16 convert (RNE), 4 elements/thread, 3 buffers in ONE launch.
// ---------------------------------------------------------------------------
__global__ __launch_bounds__(256) void cvt3_f32_bf16(
    const float* __restrict__ a, u16* __restrict__ oa, int na,
    const float* __restrict__ bsrc, u16* __restrict__ ob, int nb,
    const float* __restrict__ c, u16* __restrict__ oc, int nc)
{
    int i = (blockIdx.x * 256 + threadIdx.x) * 4;
    const float* s; u16* d;
    if (i < na)                { s = a;    d = oa; }
    else if ((i -= na) < nb)   { s = bsrc; d = ob; }
    else if ((i -= nb) < nc)   { s = c;    d = oc; }
    else return;
    const float4 f = *reinterpret_cast<const float4*>(s + i);
    u16x4 r;
    r.x = f2bf(f.x); r.y = f2bf(f.y); r.z = f2bf(f.z); r.w = f2bf(f.w);
    *reinterpret_cast<u16x4*>(d + i) = r;
}

// ---------------------------------------------------------------------------
// m97-style GEMM, BK=64 as two 32-wide panels. C = A @ Bm^T.
// Bijective XCD-chunked block swizzle (T1, proven r8: QKV 82.4 -> <74us).
// Each XCD (bid&7) owns a contiguous mt-range; within the chunk, mt-minor/
// nt-major order keeps the XCD's A-slice L2-resident while B panels stream.
// Requires nwg%8==0 and cpx%ntiles==0 (1536/24, 512/8: both hold).
// MODE 0: fp32 out + fp32 bias (projection GEMM).
// MODE 1: QKV GEMM. N=3072. Cols [0,1024) -> Q (scaled by qsc, bf16 into
//         qk[M,2048]); [1024,2048) -> K (bf16 into qk); [2048,3072) -> V,
//         written DIRECTLY TRANSPOSED into vt[(b*16+h)*64+f][T].
// ---------------------------------------------------------------------------
template<int MODE>
__global__ __launch_bounds__(256) void gemm_bt128(
    const u16* __restrict__ A,
    const u16* __restrict__ Bm,
    void* __restrict__ Cv,
    const float* __restrict__ bias,
    int M, int N, int K, int lda, int ldb, int ldc,
    float qsc, u16* __restrict__ vt)
{
    const int ntiles = N >> 7;
    const int nwg  = (M >> 7) * ntiles;
    const int cpx  = nwg >> 3;            // blocks per XCD chunk
    const int mtpc = cpx / ntiles;        // mt rows per chunk
    const int xcd  = (int)blockIdx.x & 7;
    const int lc   = (int)blockIdx.x >> 3;
    const int nt = lc / mtpc;
    const int mt = xcd * mtpc + (lc % mtpc);
    const int m0 = mt * 128, n0 = nt * 128;
    const int tid  = threadIdx.x;
    const int lane = tid & 63;
    const int l15  = lane & 15;
    const int quad = lane >> 4;
    const int wave = tid >> 6;
    const int wm = (wave >> 1) * 64;   // wave m-offset in tile
    const int wn = (wave & 1) * 64;    // wave n-offset in tile

    __shared__ u16 A_sh[2][128 * 32];  // [panel][row*32 + k], linear chunks
    __shared__ u16 B_sh[2][128 * 32];

    f32x4 acc[4][4] = {};

    // staging per panel: 512 chunks of 16B; thread t handles chunks t, t+256
    const int c0 = tid, c1 = tid + 256;
    const int ar0 = c0 >> 2, as0 = (c0 & 3) * 8;
    const int ar1 = c1 >> 2, as1 = (c1 & 3) * 8;
    const u16* Ag0 = A  + (size_t)(m0 + ar0) * lda + as0;
    const u16* Ag1 = A  + (size_t)(m0 + ar1) * lda + as1;
    const u16* Bg0 = Bm + (size_t)(n0 + ar0) * ldb + as0;
    const u16* Bg1 = Bm + (size_t)(n0 + ar1) * ldb + as1;

    for (int k0 = 0; k0 < K; k0 += 64) {
        __syncthreads();                  // prior iteration's LDS reads done
        #pragma unroll
        for (int p = 0; p < 2; ++p) {
            gload_lds16(Ag0 + k0 + p * 32, &A_sh[p][c0 * 8]);
            gload_lds16(Ag1 + k0 + p * 32, &A_sh[p][c1 * 8]);
            gload_lds16(Bg0 + k0 + p * 32, &B_sh[p][c0 * 8]);
            gload_lds16(Bg1 + k0 + p * 32, &B_sh[p][c1 * 8]);
        }
        __syncthreads();                  // drains vmcnt before barrier

        #pragma unroll
        for (int p = 0; p < 2; ++p) {
            s16x8 a[4], b[4];
            #pragma unroll
            for (int i = 0; i < 4; ++i) {
                a[i] = *reinterpret_cast<const s16x8*>(&A_sh[p][(wm + i * 16 + l15) * 32 + quad * 8]);
                b[i] = *reinterpret_cast<const s16x8*>(&B_sh[p][(wn + i * 16 + l15) * 32 + quad * 8]);
            }
            #pragma unroll
            for (int mi = 0; mi < 4; ++mi)
                #pragma unroll
                for (int ni = 0; ni < 4; ++ni)
                    acc[mi][ni] = __builtin_amdgcn_mfma_f32_16x16x32_bf16(
                        a[mi], b[ni], acc[mi][ni], 0, 0, 0);
        }
    }

    // Epilogue. C/D layout: row = quad*4 + r, col = lane&15
    #pragma unroll
    for (int ni = 0; ni < 4; ++ni) {
        const int col = n0 + wn + ni * 16 + l15;
        if (MODE == 0) {
            const float bv = bias ? bias[col] : 0.0f;
            #pragma unroll
            for (int mi = 0; mi < 4; ++mi) {
                const int row = m0 + wm + mi * 16 + quad * 4;
                #pragma unroll
                for (int r = 0; r < 4; ++r)
                    ((float*)Cv)[(size_t)(row + r) * ldc + col] = acc[mi][ni][r] + bv;
            }
        } else {
            if (col < TWO_D) {               // Q (scaled) or K -> qk buffer
                const float sc = (col < D_) ? qsc : 1.0f;
                #pragma unroll
                for (int mi = 0; mi < 4; ++mi) {
                    const int row = m0 + wm + mi * 16 + quad * 4;
                    #pragma unroll
                    for (int r = 0; r < 4; ++r)
                        ((u16*)Cv)[(size_t)(row + r) * ldc + col] = f2bf(acc[mi][ni][r] * sc);
                }
            } else {                         // V -> transposed vt, packed b64
                const int vc = col - TWO_D;  // h*64 + f
                #pragma unroll
                for (int mi = 0; mi < 4; ++mi) {
                    const int row = m0 + wm + mi * 16 + quad * 4;
                    const int bb = row >> 11, t = row & (T_ - 1);
                    u16x4 pk;
                    #pragma unroll
                    for (int r = 0; r < 4; ++r) pk[r] = f2bf(acc[mi][ni][r]);
                    *reinterpret_cast<u16x4*>(
                        vt + ((size_t)(bb * H_ * HD_) + vc) * T_ + t) = pk;
                }
            }
        }
    }
}

// ---------------------------------------------------------------------------
// Causal flash attention v6x = r8's v6s (74.1us, proven) with the VALU hog
// removed: fast_exp2 (raw v_exp_f32) + pktrunc P-pack (2 v_perm per frag).
// Per-tile VALU inventory drops ~1500 -> ~400 cyc (see fast_exp2 comment).
// Structure unchanged: 4 waves x 32 q-rows, KV-tile 64, K/V in [64][64] LDS
// with 3-bit XOR involution (write+read, 0-conflict pattern), register
// prefetch, S^T via mfma(A=kf,B=qf), b64 P writes (stride-72 P_lds),
// ones-MFMA rowsum, qmap load balance.
// ---------------------------------------------------------------------------
__global__ __launch_bounds__(256) void flash_attn6x(
    const u16* __restrict__ qk, const u16* __restrict__ vt,
    u16* __restrict__ out)   // [B*T, D] bf16
{
    const int cls = blockIdx.x >> 6;          // 0..15
    const int bh  = blockIdx.x & 63;
    const int qmap[16] = {15,14,13,12, 8,9,10,11, 7,6,5,4, 0,1,2,3};
    const int qt = qmap[cls];
    const int h = bh & 15, b = bh >> 4;
    const int q0 = qt * 128;

    __shared__ u16 K_lds[64 * 64];         // [key][feat], chunk^=(row&7)
    __shared__ u16 V_lds[64 * 64];         // [feat][key], chunk^=(row&7)
    __shared__ u16 P_lds[4 * 32 * 72];     // per-wave [qrow][key], stride 72

    const int tid = threadIdx.x;
    const int wave = tid >> 6, lane = tid & 63;
    const int l15 = lane & 15, quad = lane >> 4;
    u16* Pw = P_lds + wave * (32 * 72);

    const int w0 = q0 + wave * 32;         // wave's first q-row

    // Q fragments: 2 m-tiles x 2 k-steps (pre-scaled by cs in GEMM1)
    s16x8 qf[2][2];
    #pragma unroll
    for (int mi = 0; mi < 2; ++mi) {
        const size_t rowQ = (size_t)(b * T_ + w0 + mi * 16 + l15) * TWO_D + h * HD_;
        qf[mi][0] = load8(qk + rowQ + quad * 8);
        qf[mi][1] = load8(qk + rowQ + 32 + quad * 8);
    }

    f32x4 o[2][4] = {};
    f32x4 osum[2] = {};

    s16x8 ones;
    #pragma unroll
    for (int j = 0; j < 8; ++j) ones[j] = (short)0x3F80;   // bf16 1.0

    // staging: thread covers K rows r0,r0+32 and V feats r0,r0+32, 16B each.
    // LDS write chunk is XOR-swizzled; (r0+32)&7 == r0&7 so both rows share
    // the same swizzled chunk offset. Global source stays linear.
    const int r0 = tid >> 3;               // 0..31
    const int s0 = (tid & 7) * 8;          // u16 offset of 16B chunk (global)
    const int wsw = (((tid & 7) ^ (r0 & 7)) * 8);   // swizzled LDS chunk
    const u16* Kg0 = qk + (size_t)(b * T_ + r0)      * TWO_D + D_ + h * HD_ + s0;
    const u16* Kg1 = qk + (size_t)(b * T_ + r0 + 32) * TWO_D + D_ + h * HD_ + s0;
    const u16* Vg0 = vt + (size_t)(bh * HD_ + r0)      * T_ + s0;
    const u16* Vg1 = vt + (size_t)(bh * HD_ + r0 + 32) * T_ + s0;

    // prefetch tile 0
    s16x8 pk0 = load8(Kg0);
    s16x8 pk1 = load8(Kg1);
    s16x8 pv0 = load8(Vg0);
    s16x8 pv1 = load8(Vg1);

    // read-side swizzle: frag rows are n*16+l15 -> row&7 == l15&7
    const int rsw = l15 & 7;

    const int nkt = 2 * qt + 2;
    for (int kt = 0; kt < nkt; ++kt) {
        const int kbase = kt * 64;
        __syncthreads();                   // prior tile's LDS reads done
        *reinterpret_cast<s16x8*>(&K_lds[r0 * 64 + wsw])        = pk0;
        *reinterpret_cast<s16x8*>(&K_lds[(r0 + 32) * 64 + wsw]) = pk1;
        *reinterpret_cast<s16x8*>(&V_lds[r0 * 64 + wsw])        = pv0;
        *reinterpret_cast<s16x8*>(&V_lds[(r0 + 32) * 64 + wsw]) = pv1;
        __syncthreads();

        if (kt + 1 < nkt) {                // prefetch next tile (latency
            const int nb = kbase + 64;     //  hidden under this tile's math)
            pk0 = load8(Kg0 + (size_t)nb * TWO_D);
            pk1 = load8(Kg1 + (size_t)nb * TWO_D);
            pv0 = load8(Vg0 + nb);
            pv1 = load8(Vg1 + nb);
        }

        if (kbase <= w0 + 31) {            // wave has unmasked work here
            // S^T = K Q^T : D[m=key][n=qrow]; kf as A, qf as B (same regs)
            f32x4 st[2][4];
            #pragma unroll
            for (int n = 0; n < 4; ++n) {
                const s16x8 kf0 = *reinterpret_cast<const s16x8*>(
                    &K_lds[(n * 16 + l15) * 64 + ((quad ^ rsw) * 8)]);
                const s16x8 kf1 = *reinterpret_cast<const s16x8*>(
                    &K_lds[(n * 16 + l15) * 64 + (((quad ^ 4) ^ rsw) * 8)]);
                #pragma unroll
                for (int mi = 0; mi < 2; ++mi) {
                    f32x4 t = {};
                    t = __builtin_amdgcn_mfma_f32_16x16x32_bf16(kf0, qf[mi][0], t, 0, 0, 0);
                    t = __builtin_amdgcn_mfma_f32_16x16x32_bf16(kf1, qf[mi][1], t, 0, 0, 0);
                    st[mi][n] = t;
                }
            }

            // P = exp2(S^T): lane holds keys kbase+n*16+quad*4+{0..3} for
            // qrow w0+mi*16+l15. fast_exp2 (1 op/elem) + mask on floats +
            // pktrunc pairs (2 v_perm) -> single b64 LDS write.
            const bool diag = (kbase + 63 > w0);
            #pragma unroll
            for (int mi = 0; mi < 2; ++mi) {
                const int qr = w0 + mi * 16 + l15;
                #pragma unroll
                for (int n = 0; n < 4; ++n) {
                    const int kb = kbase + n * 16 + quad * 4;
                    float e0 = fast_exp2(st[mi][n][0]);
                    float e1 = fast_exp2(st[mi][n][1]);
                    float e2 = fast_exp2(st[mi][n][2]);
                    float e3 = fast_exp2(st[mi][n][3]);
                    if (diag) {
                        if (kb + 0 > qr) e0 = 0.0f;
                        if (kb + 1 > qr) e1 = 0.0f;
                        if (kb + 2 > qr) e2 = 0.0f;
                        if (kb + 3 > qr) e3 = 0.0f;
                    }
                    u32x2 w; w.x = pktrunc(e0, e1); w.y = pktrunc(e2, e3);
                    *reinterpret_cast<u32x2*>(
                        &Pw[(mi * 16 + l15) * 72 + n * 16 + quad * 4]) = w;
                }
            }

            // O += P V ; rowsum += P * ones (same-wave P write->read; the
            // compiler inserts the lgkmcnt wait -- m120-verified pattern)
            #pragma unroll
            for (int ks = 0; ks < 2; ++ks) {
                s16x8 pa[2];
                #pragma unroll
                for (int mi = 0; mi < 2; ++mi) {
                    pa[mi] = *reinterpret_cast<const s16x8*>(
                        &Pw[(mi * 16 + l15) * 72 + ks * 32 + quad * 8]);
                    osum[mi] = __builtin_amdgcn_mfma_f32_16x16x32_bf16(
                        pa[mi], ones, osum[mi], 0, 0, 0);
                }
                #pragma unroll
                for (int n4 = 0; n4 < 4; ++n4) {
                    const s16x8 vb = *reinterpret_cast<const s16x8*>(
                        &V_lds[(n4 * 16 + l15) * 64 + (((ks * 4 + quad) ^ rsw) * 8)]);
                    #pragma unroll
                    for (int mi = 0; mi < 2; ++mi)
                        o[mi][n4] = __builtin_amdgcn_mfma_f32_16x16x32_bf16(
                            pa[mi], vb, o[mi][n4], 0, 0, 0);
                }
            }
        }
    }

    #pragma unroll
    for (int mi = 0; mi < 2; ++mi)
        #pragma unroll
        for (int r = 0; r < 4; ++r) {
            const float inv = 1.0f / osum[mi][r];
            const size_t rowO = (size_t)(b * T_ + w0 + mi * 16 + quad * 4 + r) * D_ + h * HD_;
            #pragma unroll
            for (int n4 = 0; n4 < 4; ++n4)
                out[rowO + n4 * 16 + l15] = f2bf(o[mi][n4][r] * inv);
        }
}

// ---------------------------------------------------------------------------
extern "C" void kernel_launch(void* const* d_in, const int* in_sizes, int n_in,
                              void* d_out, int out_size, void* d_ws, size_t ws_size,
                              hipStream_t stream)
{
    const float* x     = (const float*)d_in[0];  // [B,T,D]  fp32
    const float* Wqkv  = (const float*)d_in[1];  // [3D,D]   fp32
    const float* Wproj = (const float*)d_in[2];  // [D,D]    fp32
    const float* bproj = (const float*)d_in[3];  // [D]      fp32
    float* out = (float*)d_out;                  // [B,T,D]  fp32

    const int M = B_ * T_;
    const float cs = 0.18033688011f;             // (1/sqrt(64)) * log2(e)

    // Workspace (bf16 = u16). Total 88 MB, no aliasing.
    u16* xb    = (u16*)d_ws;                              // [M, D]       16 MB
    u16* wqkvb = xb    + (size_t)M * D_;                  // [3D, D]       6 MB
    u16* wprob = wqkvb + (size_t)THREE_D * D_;            // [D, D]        2 MB
    u16* qk    = wprob + (size_t)D_ * D_;                 // [M, 2D]      32 MB
    u16* vtb   = qk    + (size_t)M * TWO_D;               // [B*H*64, T]  16 MB
    u16* attn  = vtb   + (size_t)B_ * H_ * HD_ * T_;      // [M, D]       16 MB

    // 0) fp32 -> bf16 converts (single launch, 3 segments)
    {
        const int na = M * D_, nb = THREE_D * D_, nc = D_ * D_;
        const int total = na + nb + nc;
        cvt3_f32_bf16<<<dim3((total / 4 + 255) / 256), 256, 0, stream>>>(
            x, xb, na, Wqkv, wqkvb, nb, Wproj, wprob, nc);
    }

    // 1) qkv GEMM: Q (scaled by cs) and K -> qk[M,2D]; V -> vt transposed
    gemm_bt128<1><<<dim3((M / 128) * (THREE_D / 128)), 256, 0, stream>>>(
        xb, wqkvb, qk, nullptr, M, THREE_D, D_, D_, D_, TWO_D, cs, vtb);

    // 2) causal flash attention (bf16 out)
    flash_attn6x<<<dim3(B_ * H_ * (T_ / 128)), 256, 0, stream>>>(qk, vtb, attn);

    // 3) out = attn @ Wproj^T + bproj   (fp32 out)
    gemm_bt128<0><<<dim3((M / 128) * (D_ / 128)), 256, 0, stream>>>(
        attn, wprob, out, bproj, M, D_, D_, D_, D_, D_, 1.0f, nullptr);
}

// Round 10
// 235.336 us; speedup vs baseline: 1.1881x; 1.0153x over previous
//
#include <hip/hip_runtime.h>
#include <hip/hip_bf16.h>

// Problem constants (fixed by the reference)
#define B_  4
#define T_  2048
#define D_  1024
#define H_  16
#define HD_ 64
#define THREE_D (3 * D_)
#define TWO_D   (2 * D_)

typedef short s16x8 __attribute__((ext_vector_type(8)));   // 8 bf16 (4 VGPRs)
typedef float f32x4 __attribute__((ext_vector_type(4)));   // MFMA C/D frag
typedef unsigned short u16;
typedef unsigned short u16x4 __attribute__((ext_vector_type(4)));
typedef unsigned int u32x2 __attribute__((ext_vector_type(2)));

static __device__ __forceinline__ s16x8 load8(const u16* p) {
    return *reinterpret_cast<const s16x8*>(p);
}
static __device__ __forceinline__ u16 f2bf(float f) {
    __hip_bfloat16 h = __float2bfloat16(f);
    return *reinterpret_cast<u16*>(&h);
}
// truncating pack: (trunc_bf16(hi) << 16) | trunc_bf16(lo), ONE v_perm_b32.
// Correctness-proven in v10 (passed, absmax 0.0176).
static __device__ __forceinline__ unsigned pktrunc(float lo, float hi) {
#if __has_builtin(__builtin_amdgcn_perm)
    // combo {src0:src1} bytes 7..0; sel 0x07060302 -> dst = hi[3:2]:lo[3:2]
    return __builtin_amdgcn_perm(__builtin_bit_cast(unsigned, hi),
                                 __builtin_bit_cast(unsigned, lo),
                                 0x07060302u);
#else
    return (__builtin_bit_cast(unsigned, hi) & 0xFFFF0000u) |
           (__builtin_bit_cast(unsigned, lo) >> 16);
#endif
}
// RAW-HW exp2: v_exp_f32 (1 trans-VALU op, ~1 ulp). exp2f without fast-math
// lowers to OCML __ocml_exp2_f32 (~15-20 VALU ops/elem) -- the r8->r9 fix
// (attn 74.2 -> out of top-5). Plain VALU asm is scoreboarded on CDNA
// (no MFMA-style hazard, v8 lesson applies only to MFMA).
static __device__ __forceinline__ float fast_exp2(float x) {
#if __has_builtin(__builtin_amdgcn_exp2f)
    return __builtin_amdgcn_exp2f(x);
#else
    float r;
    asm("v_exp_f32 %0, %1" : "=v"(r) : "v"(x));
    return r;
#endif
}

// global -> LDS direct DMA, 16B per lane (m97 ladder step: 517 -> 874 TF)
static __device__ __forceinline__ void gload_lds16(const u16* g, u16* l) {
#if __has_builtin(__builtin_amdgcn_global_load_lds)
    __builtin_amdgcn_global_load_lds(
        (__attribute__((address_space(1))) void*)g,
        (__attribute__((address_space(3))) void*)l, 16, 0, 0);
#else
    *reinterpret_cast<s16x8*>(l) = load8(g);
#endif
}

// ---------------------------------------------------------------------------
// fp32 -> bf16 convert (RNE), 4 elements/thread, 3 buffers in ONE launch.
// ---------------------------------------------------------------------------
__global__ __launch_bounds__(256) void cvt3_f32_bf16(
    const float* __restrict__ a, u16* __restrict__ oa, int na,
    const float* __restrict__ bsrc, u16* __restrict__ ob, int nb,
    const float* __restrict__ c, u16* __restrict__ oc, int nc)
{
    int i = (blockIdx.x * 256 + threadIdx.x) * 4;
    const float* s; u16* d;
    if (i < na)                { s = a;    d = oa; }
    else if ((i -= na) < nb)   { s = bsrc; d = ob; }
    else if ((i -= nb) < nc)   { s = c;    d = oc; }
    else return;
    const float4 f = *reinterpret_cast<const float4*>(s + i);
    u16x4 r;
    r.x = f2bf(f.x); r.y = f2bf(f.y); r.z = f2bf(f.z); r.w = f2bf(f.w);
    *reinterpret_cast<u16x4*>(d + i) = r;
}

// ---------------------------------------------------------------------------
// m97-style GEMM, BK=64 as two 32-wide panels. C = A @ Bm^T.
// r8: bijective XCD-chunked block swizzle (QKV 82.4 -> ~69us).
// NEW (r10): LDS chunk-swizzle to kill the 6.29M bank-conflict cycles.
//   Rows are 32 u16 = 4x 16B chunks; unswizzled frag reads put 8 lanes of
//   each quarter-wave batch on one 4-bank group (bank = (row&1)*16+quad*4,
//   8-way). Involution: stored chunk = logical chunk ^ ((row>>1)&3).
//   -> read banks (l15&1)*16 + ((quad^((l15>>1)&3))*4): 16 lanes over 8
//   slots = 2-way = free (m136). Write side: DMA dest stays lane-linear
//   (m104); the swizzle rides on the GLOBAL source column, permuting 16B
//   chunks within each 64B row (coalescing unchanged). Read-side XOR is a
//   per-thread constant ((l15>>1)&3) since wm+i*16 == 0 mod 16.
// MODE 0: fp32 out + fp32 bias (projection GEMM).
// MODE 1: QKV GEMM. N=3072. Cols [0,1024) -> Q (scaled by qsc, bf16 into
//         qk[M,2048]); [1024,2048) -> K (bf16 into qk); [2048,3072) -> V,
//         written DIRECTLY TRANSPOSED into vt[(b*16+h)*64+f][T].
// ---------------------------------------------------------------------------
template<int MODE>
__global__ __launch_bounds__(256) void gemm_bt128(
    const u16* __restrict__ A,
    const u16* __restrict__ Bm,
    void* __restrict__ Cv,
    const float* __restrict__ bias,
    int M, int N, int K, int lda, int ldb, int ldc,
    float qsc, u16* __restrict__ vt)
{
    const int ntiles = N >> 7;
    const int nwg  = (M >> 7) * ntiles;
    const int cpx  = nwg >> 3;            // blocks per XCD chunk
    const int mtpc = cpx / ntiles;        // mt rows per chunk
    const int xcd  = (int)blockIdx.x & 7;
    const int lc   = (int)blockIdx.x >> 3;
    const int nt = lc / mtpc;
    const int mt = xcd * mtpc + (lc % mtpc);
    const int m0 = mt * 128, n0 = nt * 128;
    const int tid  = threadIdx.x;
    const int lane = tid & 63;
    const int l15  = lane & 15;
    const int quad = lane >> 4;
    const int wave = tid >> 6;
    const int wm = (wave >> 1) * 64;   // wave m-offset in tile
    const int wn = (wave & 1) * 64;    // wave n-offset in tile

    __shared__ u16 A_sh[2][128 * 32];  // [panel][row*32 + k], chunk-swizzled
    __shared__ u16 B_sh[2][128 * 32];

    f32x4 acc[4][4] = {};

    // staging per panel: 512 chunks of 16B; thread t handles chunks t, t+256.
    // Source column = (chunk ^ ((row>>1)&3)) * 8 u16 (row = c>>2 -> c>>3).
    const int c0 = tid, c1 = tid + 256;
    const int ar0 = c0 >> 2, as0 = (((c0 & 3) ^ ((c0 >> 3) & 3)) * 8);
    const int ar1 = c1 >> 2, as1 = (((c1 & 3) ^ ((c1 >> 3) & 3)) * 8);
    const u16* Ag0 = A  + (size_t)(m0 + ar0) * lda + as0;
    const u16* Ag1 = A  + (size_t)(m0 + ar1) * lda + as1;
    const u16* Bg0 = Bm + (size_t)(n0 + ar0) * ldb + as0;
    const u16* Bg1 = Bm + (size_t)(n0 + ar1) * ldb + as1;

    // read-side swizzle constant: frag rows are (multiple of 16) + l15
    const int rsw2 = (l15 >> 1) & 3;
    const int rdo  = ((quad ^ rsw2) * 8);   // swizzled chunk offset (u16)

    for (int k0 = 0; k0 < K; k0 += 64) {
        __syncthreads();                  // prior iteration's LDS reads done
        #pragma unroll
        for (int p = 0; p < 2; ++p) {
            gload_lds16(Ag0 + k0 + p * 32, &A_sh[p][c0 * 8]);
            gload_lds16(Ag1 + k0 + p * 32, &A_sh[p][c1 * 8]);
            gload_lds16(Bg0 + k0 + p * 32, &B_sh[p][c0 * 8]);
            gload_lds16(Bg1 + k0 + p * 32, &B_sh[p][c1 * 8]);
        }
        __syncthreads();                  // drains vmcnt before barrier

        #pragma unroll
        for (int p = 0; p < 2; ++p) {
            s16x8 a[4], b[4];
            #pragma unroll
            for (int i = 0; i < 4; ++i) {
                a[i] = *reinterpret_cast<const s16x8*>(&A_sh[p][(wm + i * 16 + l15) * 32 + rdo]);
                b[i] = *reinterpret_cast<const s16x8*>(&B_sh[p][(wn + i * 16 + l15) * 32 + rdo]);
            }
            #pragma unroll
            for (int mi = 0; mi < 4; ++mi)
                #pragma unroll
                for (int ni = 0; ni < 4; ++ni)
                    acc[mi][ni] = __builtin_amdgcn_mfma_f32_16x16x32_bf16(
                        a[mi], b[ni], acc[mi][ni], 0, 0, 0);
        }
    }

    // Epilogue. C/D layout: row = quad*4 + r, col = lane&15
    #pragma unroll
    for (int ni = 0; ni < 4; ++ni) {
        const int col = n0 + wn + ni * 16 + l15;
        if (MODE == 0) {
            const float bv = bias ? bias[col] : 0.0f;
            #pragma unroll
            for (int mi = 0; mi < 4; ++mi) {
                const int row = m0 + wm + mi * 16 + quad * 4;
                #pragma unroll
                for (int r = 0; r < 4; ++r)
                    ((float*)Cv)[(size_t)(row + r) * ldc + col] = acc[mi][ni][r] + bv;
            }
        } else {
            if (col < TWO_D) {               // Q (scaled) or K -> qk buffer
                const float sc = (col < D_) ? qsc : 1.0f;
                #pragma unroll
                for (int mi = 0; mi < 4; ++mi) {
                    const int row = m0 + wm + mi * 16 + quad * 4;
                    #pragma unroll
                    for (int r = 0; r < 4; ++r)
                        ((u16*)Cv)[(size_t)(row + r) * ldc + col] = f2bf(acc[mi][ni][r] * sc);
                }
            } else {                         // V -> transposed vt, packed b64
                const int vc = col - TWO_D;  // h*64 + f
                #pragma unroll
                for (int mi = 0; mi < 4; ++mi) {
                    const int row = m0 + wm + mi * 16 + quad * 4;
                    const int bb = row >> 11, t = row & (T_ - 1);
                    u16x4 pk;
                    #pragma unroll
                    for (int r = 0; r < 4; ++r) pk[r] = f2bf(acc[mi][ni][r]);
                    *reinterpret_cast<u16x4*>(
                        vt + ((size_t)(bb * H_ * HD_) + vc) * T_ + t) = pk;
                }
            }
        }
    }
}

// ---------------------------------------------------------------------------
// Causal flash attention v6x (r9, proven): fast_exp2 + pktrunc P-pack;
// 4 waves x 32 q-rows, KV-tile 64, K/V in [64][64] LDS with 3-bit XOR
// involution (write+read), register prefetch, S^T via mfma(A=kf,B=qf),
// b64 P writes (stride-72 P_lds), ones-MFMA rowsum, qmap load balance.
// ---------------------------------------------------------------------------
__global__ __launch_bounds__(256) void flash_attn6x(
    const u16* __restrict__ qk, const u16* __restrict__ vt,
    u16* __restrict__ out)   // [B*T, D] bf16
{
    const int cls = blockIdx.x >> 6;          // 0..15
    const int bh  = blockIdx.x & 63;
    const int qmap[16] = {15,14,13,12, 8,9,10,11, 7,6,5,4, 0,1,2,3};
    const int qt = qmap[cls];
    const int h = bh & 15, b = bh >> 4;
    const int q0 = qt * 128;

    __shared__ u16 K_lds[64 * 64];         // [key][feat], chunk^=(row&7)
    __shared__ u16 V_lds[64 * 64];         // [feat][key], chunk^=(row&7)
    __shared__ u16 P_lds[4 * 32 * 72];     // per-wave [qrow][key], stride 72

    const int tid = threadIdx.x;
    const int wave = tid >> 6, lane = tid & 63;
    const int l15 = lane & 15, quad = lane >> 4;
    u16* Pw = P_lds + wave * (32 * 72);

    const int w0 = q0 + wave * 32;         // wave's first q-row

    // Q fragments: 2 m-tiles x 2 k-steps (pre-scaled by cs in GEMM1)
    s16x8 qf[2][2];
    #pragma unroll
    for (int mi = 0; mi < 2; ++mi) {
        const size_t rowQ = (size_t)(b * T_ + w0 + mi * 16 + l15) * TWO_D + h * HD_;
        qf[mi][0] = load8(qk + rowQ + quad * 8);
        qf[mi][1] = load8(qk + rowQ + 32 + quad * 8);
    }

    f32x4 o[2][4] = {};
    f32x4 osum[2] = {};

    s16x8 ones;
    #pragma unroll
    for (int j = 0; j < 8; ++j) ones[j] = (short)0x3F80;   // bf16 1.0

    // staging: thread covers K rows r0,r0+32 and V feats r0,r0+32, 16B each.
    // LDS write chunk is XOR-swizzled; (r0+32)&7 == r0&7 so both rows share
    // the same swizzled chunk offset. Global source stays linear.
    const int r0 = tid >> 3;               // 0..31
    const int s0 = (tid & 7) * 8;          // u16 offset of 16B chunk (global)
    const int wsw = (((tid & 7) ^ (r0 & 7)) * 8);   // swizzled LDS chunk
    const u16* Kg0 = qk + (size_t)(b * T_ + r0)      * TWO_D + D_ + h * HD_ + s0;
    const u16* Kg1 = qk + (size_t)(b * T_ + r0 + 32) * TWO_D + D_ + h * HD_ + s0;
    const u16* Vg0 = vt + (size_t)(bh * HD_ + r0)      * T_ + s0;
    const u16* Vg1 = vt + (size_t)(bh * HD_ + r0 + 32) * T_ + s0;

    // prefetch tile 0
    s16x8 pk0 = load8(Kg0);
    s16x8 pk1 = load8(Kg1);
    s16x8 pv0 = load8(Vg0);
    s16x8 pv1 = load8(Vg1);

    // read-side swizzle: frag rows are n*16+l15 -> row&7 == l15&7
    const int rsw = l15 & 7;

    const int nkt = 2 * qt + 2;
    for (int kt = 0; kt < nkt; ++kt) {
        const int kbase = kt * 64;
        __syncthreads();                   // prior tile's LDS reads done
        *reinterpret_cast<s16x8*>(&K_lds[r0 * 64 + wsw])        = pk0;
        *reinterpret_cast<s16x8*>(&K_lds[(r0 + 32) * 64 + wsw]) = pk1;
        *reinterpret_cast<s16x8*>(&V_lds[r0 * 64 + wsw])        = pv0;
        *reinterpret_cast<s16x8*>(&V_lds[(r0 + 32) * 64 + wsw]) = pv1;
        __syncthreads();

        if (kt + 1 < nkt) {                // prefetch next tile (latency
            const int nb = kbase + 64;     //  hidden under this tile's math)
            pk0 = load8(Kg0 + (size_t)nb * TWO_D);
            pk1 = load8(Kg1 + (size_t)nb * TWO_D);
            pv0 = load8(Vg0 + nb);
            pv1 = load8(Vg1 + nb);
        }

        if (kbase <= w0 + 31) {            // wave has unmasked work here
            // S^T = K Q^T : D[m=key][n=qrow]; kf as A, qf as B (same regs)
            f32x4 st[2][4];
            #pragma unroll
            for (int n = 0; n < 4; ++n) {
                const s16x8 kf0 = *reinterpret_cast<const s16x8*>(
                    &K_lds[(n * 16 + l15) * 64 + ((quad ^ rsw) * 8)]);
                const s16x8 kf1 = *reinterpret_cast<const s16x8*>(
                    &K_lds[(n * 16 + l15) * 64 + (((quad ^ 4) ^ rsw) * 8)]);
                #pragma unroll
                for (int mi = 0; mi < 2; ++mi) {
                    f32x4 t = {};
                    t = __builtin_amdgcn_mfma_f32_16x16x32_bf16(kf0, qf[mi][0], t, 0, 0, 0);
                    t = __builtin_amdgcn_mfma_f32_16x16x32_bf16(kf1, qf[mi][1], t, 0, 0, 0);
                    st[mi][n] = t;
                }
            }

            // P = exp2(S^T): lane holds keys kbase+n*16+quad*4+{0..3} for
            // qrow w0+mi*16+l15. fast_exp2 (1 op/elem) + mask on floats +
            // pktrunc pairs (2 v_perm) -> single b64 LDS write.
            const bool diag = (kbase + 63 > w0);
            #pragma unroll
            for (int mi = 0; mi < 2; ++mi) {
                const int qr = w0 + mi * 16 + l15;
                #pragma unroll
                for (int n = 0; n < 4; ++n) {
                    const int kb = kbase + n * 16 + quad * 4;
                    float e0 = fast_exp2(st[mi][n][0]);
                    float e1 = fast_exp2(st[mi][n][1]);
                    float e2 = fast_exp2(st[mi][n][2]);
                    float e3 = fast_exp2(st[mi][n][3]);
                    if (diag) {
                        if (kb + 0 > qr) e0 = 0.0f;
                        if (kb + 1 > qr) e1 = 0.0f;
                        if (kb + 2 > qr) e2 = 0.0f;
                        if (kb + 3 > qr) e3 = 0.0f;
                    }
                    u32x2 w; w.x = pktrunc(e0, e1); w.y = pktrunc(e2, e3);
                    *reinterpret_cast<u32x2*>(
                        &Pw[(mi * 16 + l15) * 72 + n * 16 + quad * 4]) = w;
                }
            }

            // O += P V ; rowsum += P * ones (same-wave P write->read; the
            // compiler inserts the lgkmcnt wait -- m120-verified pattern)
            #pragma unroll
            for (int ks = 0; ks < 2; ++ks) {
                s16x8 pa[2];
                #pragma unroll
                for (int mi = 0; mi < 2; ++mi) {
                    pa[mi] = *reinterpret_cast<const s16x8*>(
                        &Pw[(mi * 16 + l15) * 72 + ks * 32 + quad * 8]);
                    osum[mi] = __builtin_amdgcn_mfma_f32_16x16x32_bf16(
                        pa[mi], ones, osum[mi], 0, 0, 0);
                }
                #pragma unroll
                for (int n4 = 0; n4 < 4; ++n4) {
                    const s16x8 vb = *reinterpret_cast<const s16x8*>(
                        &V_lds[(n4 * 16 + l15) * 64 + (((ks * 4 + quad) ^ rsw) * 8)]);
                    #pragma unroll
                    for (int mi = 0; mi < 2; ++mi)
                        o[mi][n4] = __builtin_amdgcn_mfma_f32_16x16x32_bf16(
                            pa[mi], vb, o[mi][n4], 0, 0, 0);
                }
            }
        }
    }

    #pragma unroll
    for (int mi = 0; mi < 2; ++mi)
        #pragma unroll
        for (int r = 0; r < 4; ++r) {
            const float inv = 1.0f / osum[mi][r];
            const size_t rowO = (size_t)(b * T_ + w0 + mi * 16 + quad * 4 + r) * D_ + h * HD_;
            #pragma unroll
            for (int n4 = 0; n4 < 4; ++n4)
                out[rowO + n4 * 16 + l15] = f2bf(o[mi][n4][r] * inv);
        }
}

// ---------------------------------------------------------------------------
extern "C" void kernel_launch(void* const* d_in, const int* in_sizes, int n_in,
                              void* d_out, int out_size, void* d_ws, size_t ws_size,
                              hipStream_t stream)
{
    const float* x     = (const float*)d_in[0];  // [B,T,D]  fp32
    const float* Wqkv  = (const float*)d_in[1];  // [3D,D]   fp32
    const float* Wproj = (const float*)d_in[2];  // [D,D]    fp32
    const float* bproj = (const float*)d_in[3];  // [D]      fp32
    float* out = (float*)d_out;                  // [B,T,D]  fp32

    const int M = B_ * T_;
    const float cs = 0.18033688011f;             // (1/sqrt(64)) * log2(e)

    // Workspace (bf16 = u16). Total 88 MB, no aliasing.
    u16* xb    = (u16*)d_ws;                              // [M, D]       16 MB
    u16* wqkvb = xb    + (size_t)M * D_;                  // [3D, D]       6 MB
    u16* wprob = wqkvb + (size_t)THREE_D * D_;            // [D, D]        2 MB
    u16* qk    = wprob + (size_t)D_ * D_;                 // [M, 2D]      32 MB
    u16* vtb   = qk    + (size_t)M * TWO_D;               // [B*H*64, T]  16 MB
    u16* attn  = vtb   + (size_t)B_ * H_ * HD_ * T_;      // [M, D]       16 MB

    // 0) fp32 -> bf16 converts (single launch, 3 segments)
    {
        const int na = M * D_, nb = THREE_D * D_, nc = D_ * D_;
        const int total = na + nb + nc;
        cvt3_f32_bf16<<<dim3((total / 4 + 255) / 256), 256, 0, stream>>>(
            x, xb, na, Wqkv, wqkvb, nb, Wproj, wprob, nc);
    }

    // 1) qkv GEMM: Q (scaled by cs) and K -> qk[M,2D]; V -> vt transposed
    gemm_bt128<1><<<dim3((M / 128) * (THREE_D / 128)), 256, 0, stream>>>(
        xb, wqkvb, qk, nullptr, M, THREE_D, D_, D_, D_, TWO_D, cs, vtb);

    // 2) causal flash attention (bf16 out)
    flash_attn6x<<<dim3(B_ * H_ * (T_ / 128)), 256, 0, stream>>>(qk, vtb, attn);

    // 3) out = attn @ Wproj^T + bproj   (fp32 out)
    gemm_bt128<0><<<dim3((M / 128) * (D_ / 128)), 256, 0, stream>>>(
        attn, wprob, out, bproj, M, D_, D_, D_, D_, D_, 1.0f, nullptr);
}